// Round 2
// baseline (7035.736 us; speedup 1.0000x reference)
//
#include <hip/hip_runtime.h>
#include <hip/hip_bf16.h>
#include <cstdint>

using u16 = unsigned short;
typedef short s16x8 __attribute__((ext_vector_type(8)));
typedef float f32x4 __attribute__((ext_vector_type(4)));

// ---------- helpers ----------
__device__ __forceinline__ float b2f(u16 b) {
    union { unsigned u; float f; } z; z.u = ((unsigned)b) << 16; return z.f;
}
__device__ __forceinline__ u16 f2b(float f) {
    union { float f; unsigned u; } z; z.f = f;
    return (u16)((z.u + 0x7fffu + ((z.u >> 16) & 1u)) >> 16);
}
__device__ __forceinline__ float gelu_f(float x) {
    return 0.5f * x * (1.0f + erff(x * 0.70710678118654752440f));
}
__device__ __forceinline__ void gl2lds16(const void* g, void* l) {
    __builtin_amdgcn_global_load_lds(
        (const __attribute__((address_space(1))) void*)g,
        (__attribute__((address_space(3))) void*)l, 16, 0, 0);
}

enum { F_BIAS = 1, F_GELU = 2, F_RANK3 = 4, F_RESIDF = 8, F_RESIDH = 16,
       F_DEG = 32, F_OUTF = 64, F_OUTH = 128 };

// ---------- GEMM: C = epilogue(A_bf16[M x 512] @ Bt_bf16[512 x 512]^T) ----------
// Bt stored N-major (transposed weights); 128x128 tile, 4 waves (2x2), BK=32.
// f32 reads/writes (srcF/Cf/river/deg) are guarded by rr < Mreal (d_out has
// exactly Mreal rows). bf16 buffers have Mpad rows; Ch stores are unguarded.
template<int EPI>
__global__ __launch_bounds__(256, 2) void gemm_k(
    const u16* __restrict__ A, const u16* __restrict__ Bt,
    float* __restrict__ Cf, u16* __restrict__ Ch,
    const float* __restrict__ srcF, const u16* __restrict__ srcH,
    const float* __restrict__ bias, const float* __restrict__ bias2,
    const int* __restrict__ deg, const float* __restrict__ river,
    const float* __restrict__ w1tail, int Mreal)
{
    __shared__ __align__(16) u16 As[128 * 32];
    __shared__ __align__(16) u16 Bs[128 * 32];

    const int tid  = threadIdx.x;
    const int lane = tid & 63;
    const int wid  = tid >> 6;
    const int wr   = wid >> 1;
    const int wc   = wid & 1;
    const int fr   = lane & 15;
    const int fq   = lane >> 4;

    const long arow = (long)blockIdx.x * 128 + (wid << 4) + (lane >> 2);
    const long brow = (long)blockIdx.y * 128 + (wid << 4) + (lane >> 2);
    const int  kofs = (lane & 3) << 3;
    u16* asw = As + (wid << 9);
    u16* bsw = Bs + (wid << 9);

    f32x4 acc[4][4];
#pragma unroll
    for (int m = 0; m < 4; m++)
#pragma unroll
        for (int n = 0; n < 4; n++) { f32x4 z = {0.f, 0.f, 0.f, 0.f}; acc[m][n] = z; }

    for (int kt = 0; kt < 512; kt += 32) {
        gl2lds16(A  + arow * 512 + kt + kofs,        asw);
        gl2lds16(A  + (arow + 64) * 512 + kt + kofs, asw + 2048);
        gl2lds16(Bt + brow * 512 + kt + kofs,        bsw);
        gl2lds16(Bt + (brow + 64) * 512 + kt + kofs, bsw + 2048);
        __syncthreads();

        s16x8 af[4], bf[4];
#pragma unroll
        for (int m = 0; m < 4; m++)
            af[m] = *(const s16x8*)(As + (((wr << 6) + (m << 4) + fr) << 5) + (fq << 3));
#pragma unroll
        for (int n = 0; n < 4; n++)
            bf[n] = *(const s16x8*)(Bs + (((wc << 6) + (n << 4) + fr) << 5) + (fq << 3));
#pragma unroll
        for (int m = 0; m < 4; m++)
#pragma unroll
            for (int n = 0; n < 4; n++)
                acc[m][n] = __builtin_amdgcn_mfma_f32_16x16x32_bf16(af[m], bf[n], acc[m][n], 0, 0, 0);
        __syncthreads();
    }

    // ---------- epilogue ----------
    const int colbase = (blockIdx.y << 7) + (wc << 6);
#pragma unroll
    for (int m = 0; m < 4; m++) {
        const int row0 = (blockIdx.x << 7) + (wr << 6) + (m << 4) + (fq << 2);
#pragma unroll
        for (int r = 0; r < 4; r++) {
            const int rr = row0 + r;
            const bool real = rr < Mreal;
            float rv0 = 0.f, rv1 = 0.f, rv2 = 0.f;
            if constexpr (EPI & F_RANK3) {
                if (real) { rv0 = river[rr * 3]; rv1 = river[rr * 3 + 1]; rv2 = river[rr * 3 + 2]; }
            }
            float dg = 0.f;
            if constexpr (EPI & F_DEG) { if (real) dg = (float)deg[rr]; }
#pragma unroll
            for (int n = 0; n < 4; n++) {
                const int col = colbase + (n << 4) + fr;
                float v = acc[m][n][r];
                if constexpr (EPI & F_BIAS)   v += bias[col];
                if constexpr (EPI & F_RANK3)  v += rv0 * w1tail[col] + rv1 * w1tail[512 + col] + rv2 * w1tail[1024 + col];
                if constexpr (EPI & F_GELU)   v = gelu_f(v);
                if constexpr (EPI & F_RESIDF) { if (real) v += srcF[(long)rr * 512 + col]; }
                if constexpr (EPI & F_RESIDH) { if (real) v += b2f(srcH[(long)rr * 512 + col]); }
                if constexpr (EPI & F_DEG)    v += dg * bias2[col];
                if constexpr (EPI & F_OUTF)   { if (real) Cf[(long)rr * 512 + col] = v; }
                if constexpr (EPI & F_OUTH)   Ch[(long)rr * 512 + col] = f2b(v);
            }
        }
    }
}

// ---------- edge phase: Hagg[t] += gelu(A[s] + B[t] + bm1) ----------
__global__ __launch_bounds__(256) void edge_k(
    const int* __restrict__ ed, const u16* __restrict__ An, const u16* __restrict__ Bn,
    const float* __restrict__ bm1, float* __restrict__ Hagg, int nE)
{
    const int e = (blockIdx.x << 2) + (threadIdx.x >> 6);
    if (e >= nE) return;
    const int lane = threadIdx.x & 63;
    const int s = ed[2 * e], t = ed[2 * e + 1];
    const int c = lane << 3;
    s16x8 av = *(const s16x8*)(An + (long)s * 512 + c);
    s16x8 bv = *(const s16x8*)(Bn + (long)t * 512 + c);
    const float4* bmv = (const float4*)(bm1 + c);
    float4 bm0 = bmv[0], bm1v = bmv[1];
    float bmz[8] = { bm0.x, bm0.y, bm0.z, bm0.w, bm1v.x, bm1v.y, bm1v.z, bm1v.w };
    float* hp = Hagg + (long)t * 512 + c;
#pragma unroll
    for (int j = 0; j < 8; j++) {
        float x = b2f((u16)av[j]) + b2f((u16)bv[j]) + bmz[j];
        atomicAdd(hp + j, gelu_f(x));
    }
}

// ---------- degree histogram ----------
__global__ __launch_bounds__(256) void deg_k(const int* __restrict__ ed, int* __restrict__ deg, int nE)
{
    const int e = blockIdx.x * 256 + threadIdx.x;
    if (e < nE) atomicAdd(&deg[ed[2 * e + 1]], 1);
}

// ---------- f32 -> bf16 (flat, region beyond nSrc zero-filled) ----------
__global__ __launch_bounds__(256) void cvt_pad_k(
    const float* __restrict__ src, u16* __restrict__ dst, long nSrc, long nTot)
{
    const long i = ((long)blockIdx.x * 256 + threadIdx.x) * 8;
    if (i >= nTot) return;
    s16x8 v;
    if (i + 8 <= nSrc) {
        const float4* s4 = (const float4*)(src + i);
        float4 a = s4[0], b = s4[1];
        v[0] = (short)f2b(a.x); v[1] = (short)f2b(a.y); v[2] = (short)f2b(a.z); v[3] = (short)f2b(a.w);
        v[4] = (short)f2b(b.x); v[5] = (short)f2b(b.y); v[6] = (short)f2b(b.z); v[7] = (short)f2b(b.w);
    } else {
#pragma unroll
        for (int j = 0; j < 8; j++) v[j] = (i + j < nSrc) ? (short)f2b(src[i + j]) : (short)0;
    }
    *(s16x8*)(dst + i) = v;
}

// ---------- weight transpose + convert: Wt[n*K+k] = bf16(W[(k+off)*N + n]) ----------
__global__ __launch_bounds__(256) void wtrans_k(
    const float* __restrict__ W, u16* __restrict__ Wt, int K, int N, int rowOff)
{
    const int idx = blockIdx.x * 256 + threadIdx.x;
    if (idx >= K * N) return;
    const int n = idx / K, k = idx % K;
    Wt[idx] = f2b(W[(long)(k + rowOff) * N + n]);
}

extern "C" void kernel_launch(void* const* d_in, const int* in_sizes, int n_in,
                              void* d_out, int out_size, void* d_ws, size_t ws_size,
                              hipStream_t stream)
{
    const float* nodef = (const float*)d_in[0];
    const float* river = (const float*)d_in[1];
    const int*   edges = (const int*)d_in[2];
    const float* W1  = (const float*)d_in[3];
    const float* b1  = (const float*)d_in[4];
    const float* W2  = (const float*)d_in[5];
    const float* b2  = (const float*)d_in[6];
    const float* Wm1 = (const float*)d_in[7];
    const float* bm1 = (const float*)d_in[8];
    const float* Wm2 = (const float*)d_in[9];
    const float* bm2 = (const float*)d_in[10];
    float* out = (float*)d_out;
    (void)n_in; (void)out_size;

    const int M = 50000, Mpad = 50048, H = 512;
    const int nE = in_sizes[2] / 2;
    const size_t nElem = (size_t)Mpad * H;   // 25,624,576
    const size_t nOut  = (size_t)M * H;      // 25,600,000

    // ---------- workspace layout (lean region first, then Hagg) ----------
    char* ws = (char*)d_ws;
    size_t off = 0;
    auto alloc = [&](size_t bytes) { void* p = ws + off; off += (bytes + 255) & ~(size_t)255; return p; };
    u16* feats16 = (u16*)alloc(nElem * 2);           // running features, bf16
    u16* s4      = (u16*)alloc(nElem * 2);           // h1_16 / A16 / Hg16
    u16* s5      = (u16*)alloc(nElem * 2);           // nf16 / B16
    u16* W1t     = (u16*)alloc(512 * 512 * 2);
    u16* W2t     = (u16*)alloc(512 * 512 * 2);
    u16* Wm1at   = (u16*)alloc(512 * 512 * 2);
    u16* Wm1bt   = (u16*)alloc(512 * 512 * 2);
    u16* Wm2t    = (u16*)alloc(512 * 512 * 2);
    int* deg     = (int*)alloc((size_t)Mpad * 4);
    const size_t NEED_LEAN = off;                    // ~157 MB
    float* HaggWs = (float*)alloc(nElem * 4);
    const size_t NEED_FULL = off;                    // ~259 MB

    if (ws_size < NEED_LEAN) return;                 // tripwire: clean absmax fail
    const bool full = ws_size >= NEED_FULL;
    // full: feats f32 lives in d_out, Hagg in ws. lean: Hagg lives in d_out,
    // residual carried in bf16 (feats16).
    float* Hagg = full ? HaggWs : out;
    const long haggElems = full ? (long)nElem : (long)nOut;

    const dim3 ggrid(Mpad / 128, H / 128, 1);
    const dim3 gblk(256, 1, 1);
    const int cvtBlocks = (int)(nElem / 8 / 256);    // 12512, exact

    hipMemsetAsync(deg, 0, (size_t)Mpad * 4, stream);
    deg_k<<<dim3((nE + 255) / 256), gblk, 0, stream>>>(edges, deg, nE);

    wtrans_k<<<dim3(1024), gblk, 0, stream>>>(W1,  W1t,   512, 512, 0);
    wtrans_k<<<dim3(1024), gblk, 0, stream>>>(W2,  W2t,   512, 512, 0);
    wtrans_k<<<dim3(1024), gblk, 0, stream>>>(Wm1, Wm1at, 512, 512, 0);
    wtrans_k<<<dim3(1024), gblk, 0, stream>>>(Wm1, Wm1bt, 512, 512, 512);
    wtrans_k<<<dim3(1024), gblk, 0, stream>>>(Wm2, Wm2t,  512, 512, 0);

    // node_features -> bf16 into s5 (padded rows zeroed)
    cvt_pad_k<<<dim3(cvtBlocks), gblk, 0, stream>>>(nodef, s5, (long)nOut, (long)nElem);

    // h1 = gelu(x @ W1 + b1) with rank-3 river term fused  -> s4 (bf16)
    gemm_k<F_BIAS | F_RANK3 | F_GELU | F_OUTH><<<ggrid, gblk, 0, stream>>>(
        s5, W1t, nullptr, s4, nullptr, nullptr, b1, nullptr, nullptr, river, W1 + 512 * 512, M);
    // feats = h1 @ W2 + b2
    if (full)
        gemm_k<F_BIAS | F_OUTF | F_OUTH><<<ggrid, gblk, 0, stream>>>(
            s4, W2t, out, feats16, nullptr, nullptr, b2, nullptr, nullptr, nullptr, nullptr, M);
    else
        gemm_k<F_BIAS | F_OUTH><<<ggrid, gblk, 0, stream>>>(
            s4, W2t, nullptr, feats16, nullptr, nullptr, b2, nullptr, nullptr, nullptr, nullptr, M);

    for (int r = 0; r < 3; r++) {
        // A = feats @ Wm1_top -> s4 ; B = feats @ Wm1_bot -> s5
        gemm_k<F_OUTH><<<ggrid, gblk, 0, stream>>>(
            feats16, Wm1at, nullptr, s4, nullptr, nullptr, nullptr, nullptr, nullptr, nullptr, nullptr, M);
        gemm_k<F_OUTH><<<ggrid, gblk, 0, stream>>>(
            feats16, Wm1bt, nullptr, s5, nullptr, nullptr, nullptr, nullptr, nullptr, nullptr, nullptr, M);
        // Hagg[t] = sum_e gelu(A[s_e] + B[t] + bm1)
        hipMemsetAsync(Hagg, 0, (size_t)haggElems * 4, stream);
        edge_k<<<dim3((nE + 3) / 4), gblk, 0, stream>>>(edges, s4, s5, bm1, Hagg, nE);
        // Hg16 = bf16(Hagg), padded rows zeroed -> s4 (A16 dead)
        cvt_pad_k<<<dim3(cvtBlocks), gblk, 0, stream>>>(Hagg, s4, haggElems, (long)nElem);
        // feats = feats + Hagg @ Wm2 + deg * bm2
        if (full) {
            if (r < 2)
                gemm_k<F_RESIDF | F_DEG | F_OUTF | F_OUTH><<<ggrid, gblk, 0, stream>>>(
                    s4, Wm2t, out, feats16, out, nullptr, nullptr, bm2, deg, nullptr, nullptr, M);
            else
                gemm_k<F_RESIDF | F_DEG | F_OUTF><<<ggrid, gblk, 0, stream>>>(
                    s4, Wm2t, out, nullptr, out, nullptr, nullptr, bm2, deg, nullptr, nullptr, M);
        } else {
            if (r < 2)
                gemm_k<F_RESIDH | F_DEG | F_OUTH><<<ggrid, gblk, 0, stream>>>(
                    s4, Wm2t, nullptr, feats16, nullptr, feats16, nullptr, bm2, deg, nullptr, nullptr, M);
            else
                gemm_k<F_RESIDH | F_DEG | F_OUTF><<<ggrid, gblk, 0, stream>>>(
                    s4, Wm2t, out, nullptr, nullptr, feats16, nullptr, bm2, deg, nullptr, nullptr, M);
        }
    }
}

// Round 3
// 1047.602 us; speedup vs baseline: 6.7160x; 6.7160x over previous
//
#include <hip/hip_runtime.h>
#include <hip/hip_bf16.h>
#include <cstdint>

using u16 = unsigned short;
typedef short s16x8 __attribute__((ext_vector_type(8)));
typedef float f32x4 __attribute__((ext_vector_type(4)));

// ---------- helpers ----------
__device__ __forceinline__ float b2f(u16 b) {
    union { unsigned u; float f; } z; z.u = ((unsigned)b) << 16; return z.f;
}
__device__ __forceinline__ u16 f2b(float f) {
    union { float f; unsigned u; } z; z.f = f;
    return (u16)((z.u + 0x7fffu + ((z.u >> 16) & 1u)) >> 16);
}
__device__ __forceinline__ float gelu_f(float x) {
    return 0.5f * x * (1.0f + erff(x * 0.70710678118654752440f));
}
__device__ __forceinline__ void gl2lds16(const void* g, void* l) {
    __builtin_amdgcn_global_load_lds(
        (const __attribute__((address_space(1))) void*)g,
        (__attribute__((address_space(3))) void*)l, 16, 0, 0);
}

enum { F_BIAS = 1, F_GELU = 2, F_RANK3 = 4, F_RESIDF = 8, F_RESIDH = 16,
       F_DEG = 32, F_OUTF = 64, F_OUTH = 128 };

// ---------- GEMM: C = epilogue(A_bf16[M x 512] @ Bt_bf16[N x 512]^T) ----------
template<int EPI>
__global__ __launch_bounds__(256, 2) void gemm_k(
    const u16* __restrict__ A, const u16* __restrict__ Bt,
    float* __restrict__ Cf, u16* __restrict__ Ch,
    const float* __restrict__ srcF, const u16* __restrict__ srcH,
    const float* __restrict__ bias, const float* __restrict__ bias2,
    const int* __restrict__ deg, const float* __restrict__ river,
    const float* __restrict__ w1tail, int Mreal, int ldh)
{
    __shared__ __align__(16) u16 As[128 * 32];
    __shared__ __align__(16) u16 Bs[128 * 32];

    const int tid  = threadIdx.x;
    const int lane = tid & 63;
    const int wid  = tid >> 6;
    const int wr   = wid >> 1;
    const int wc   = wid & 1;
    const int fr   = lane & 15;
    const int fq   = lane >> 4;

    const long arow = (long)blockIdx.x * 128 + (wid << 4) + (lane >> 2);
    const long brow = (long)blockIdx.y * 128 + (wid << 4) + (lane >> 2);
    const int  kofs = (lane & 3) << 3;
    u16* asw = As + (wid << 9);
    u16* bsw = Bs + (wid << 9);

    f32x4 acc[4][4];
#pragma unroll
    for (int m = 0; m < 4; m++)
#pragma unroll
        for (int n = 0; n < 4; n++) { f32x4 z = {0.f, 0.f, 0.f, 0.f}; acc[m][n] = z; }

    for (int kt = 0; kt < 512; kt += 32) {
        gl2lds16(A  + arow * 512 + kt + kofs,        asw);
        gl2lds16(A  + (arow + 64) * 512 + kt + kofs, asw + 2048);
        gl2lds16(Bt + brow * 512 + kt + kofs,        bsw);
        gl2lds16(Bt + (brow + 64) * 512 + kt + kofs, bsw + 2048);
        __syncthreads();

        s16x8 af[4], bf[4];
#pragma unroll
        for (int m = 0; m < 4; m++)
            af[m] = *(const s16x8*)(As + (((wr << 6) + (m << 4) + fr) << 5) + (fq << 3));
#pragma unroll
        for (int n = 0; n < 4; n++)
            bf[n] = *(const s16x8*)(Bs + (((wc << 6) + (n << 4) + fr) << 5) + (fq << 3));
#pragma unroll
        for (int m = 0; m < 4; m++)
#pragma unroll
            for (int n = 0; n < 4; n++)
                acc[m][n] = __builtin_amdgcn_mfma_f32_16x16x32_bf16(af[m], bf[n], acc[m][n], 0, 0, 0);
        __syncthreads();
    }

    const int colbase = (blockIdx.y << 7) + (wc << 6);
#pragma unroll
    for (int m = 0; m < 4; m++) {
        const int row0 = (blockIdx.x << 7) + (wr << 6) + (m << 4) + (fq << 2);
#pragma unroll
        for (int r = 0; r < 4; r++) {
            const int rr = row0 + r;
            const bool real = rr < Mreal;
            float rv0 = 0.f, rv1 = 0.f, rv2 = 0.f;
            if constexpr (EPI & F_RANK3) {
                if (real) { rv0 = river[rr * 3]; rv1 = river[rr * 3 + 1]; rv2 = river[rr * 3 + 2]; }
            }
            float dg = 0.f;
            if constexpr (EPI & F_DEG) { if (real) dg = (float)deg[rr]; }
#pragma unroll
            for (int n = 0; n < 4; n++) {
                const int col = colbase + (n << 4) + fr;
                float v = acc[m][n][r];
                if constexpr (EPI & F_BIAS)   v += bias[col];
                if constexpr (EPI & F_RANK3)  v += rv0 * w1tail[col] + rv1 * w1tail[512 + col] + rv2 * w1tail[1024 + col];
                if constexpr (EPI & F_GELU)   v = gelu_f(v);
                if constexpr (EPI & F_RESIDF) { if (real) v += srcF[(long)rr * 512 + col]; }
                if constexpr (EPI & F_RESIDH) { if (real) v += b2f(srcH[(long)rr * 512 + col]); }
                if constexpr (EPI & F_DEG)    v += dg * bias2[col];
                if constexpr (EPI & F_OUTF)   { if (real) Cf[(long)rr * 512 + col] = v; }
                if constexpr (EPI & F_OUTH)   Ch[(long)rr * ldh + col] = f2b(v);
            }
        }
    }
}

// ---------- CSR build ----------
__global__ __launch_bounds__(256) void deg_k(const int* __restrict__ ed, int* __restrict__ deg, int nE)
{
    const int e = blockIdx.x * 256 + threadIdx.x;
    if (e < nE) atomicAdd(&deg[ed[2 * e + 1]], 1);
}

__global__ __launch_bounds__(256) void scan_k(const int* __restrict__ deg, int* __restrict__ rowptr, int n)
{
    __shared__ int part[256];
    const int tid = threadIdx.x;
    const int per = (n + 255) / 256;
    const int start = tid * per;
    int sum = 0;
    for (int i = start; i < start + per && i < n; i++) sum += deg[i];
    part[tid] = sum;
    __syncthreads();
    if (tid == 0) {
        int acc = 0;
        for (int i = 0; i < 256; i++) { int v = part[i]; part[i] = acc; acc += v; }
    }
    __syncthreads();
    int acc = part[tid];
    for (int i = start; i < start + per && i < n; i++) { rowptr[i] = acc; acc += deg[i]; }
}

__global__ __launch_bounds__(256) void scat_k(
    const int* __restrict__ ed, const int* __restrict__ rowptr,
    int* __restrict__ cursor, int* __restrict__ csr, int nE)
{
    const int e = blockIdx.x * 256 + threadIdx.x;
    if (e >= nE) return;
    const int t = ed[2 * e + 1];
    const int p = atomicAdd(&cursor[t], 1);
    csr[rowptr[t] + p] = ed[2 * e];
}

// ---------- gather: Hg[t] = bf16( sum_{s in in(t)} gelu(A[s] + B[t] + bm1) ) ----------
__global__ __launch_bounds__(256) void gather_k(
    const int* __restrict__ rowptr, const int* __restrict__ degv,
    const int* __restrict__ csr, const u16* __restrict__ AB,
    const float* __restrict__ bm1, u16* __restrict__ Hg, int nNodes)
{
    const int t = (blockIdx.x << 2) + (threadIdx.x >> 6);
    if (t >= nNodes) return;
    const int lane = threadIdx.x & 63;
    const int c = lane << 3;
    float acc[8] = {0.f, 0.f, 0.f, 0.f, 0.f, 0.f, 0.f, 0.f};
    const int d = degv[t];
    if (d > 0) {
        s16x8 bv = *(const s16x8*)(AB + (long)t * 1024 + 512 + c);
        const float4* bmv = (const float4*)(bm1 + c);
        float4 q0 = bmv[0], q1 = bmv[1];
        float base[8] = { q0.x, q0.y, q0.z, q0.w, q1.x, q1.y, q1.z, q1.w };
#pragma unroll
        for (int j = 0; j < 8; j++) base[j] += b2f((u16)bv[j]);
        const int p0 = rowptr[t];
        for (int i = 0; i < d; i++) {
            const int s = csr[p0 + i];
            s16x8 av = *(const s16x8*)(AB + (long)s * 1024 + c);
#pragma unroll
            for (int j = 0; j < 8; j++) acc[j] += gelu_f(b2f((u16)av[j]) + base[j]);
        }
    }
    s16x8 o;
#pragma unroll
    for (int j = 0; j < 8; j++) o[j] = (short)f2b(acc[j]);
    *(s16x8*)(Hg + (long)t * 512 + c) = o;
}

// ---------- lean fallback: atomic edge scatter into f32 Hagg ----------
__global__ __launch_bounds__(256) void edge_atomic_k(
    const int* __restrict__ ed, const u16* __restrict__ AB,
    const float* __restrict__ bm1, float* __restrict__ Hagg, int nE)
{
    const int e = (blockIdx.x << 2) + (threadIdx.x >> 6);
    if (e >= nE) return;
    const int lane = threadIdx.x & 63;
    const int s = ed[2 * e], t = ed[2 * e + 1];
    const int c = lane << 3;
    s16x8 av = *(const s16x8*)(AB + (long)s * 1024 + c);
    s16x8 bv = *(const s16x8*)(AB + (long)t * 1024 + 512 + c);
    const float4* bmv = (const float4*)(bm1 + c);
    float4 q0 = bmv[0], q1 = bmv[1];
    float bmz[8] = { q0.x, q0.y, q0.z, q0.w, q1.x, q1.y, q1.z, q1.w };
    float* hp = Hagg + (long)t * 512 + c;
#pragma unroll
    for (int j = 0; j < 8; j++)
        atomicAdd(hp + j, gelu_f(b2f((u16)av[j]) + b2f((u16)bv[j]) + bmz[j]));
}

// ---------- f32 -> bf16 ----------
__global__ __launch_bounds__(256) void cvt_pad_k(
    const float* __restrict__ src, u16* __restrict__ dst, long nSrc, long nTot)
{
    const long i = ((long)blockIdx.x * 256 + threadIdx.x) * 8;
    if (i >= nTot) return;
    s16x8 v;
    if (i + 8 <= nSrc) {
        const float4* s4 = (const float4*)(src + i);
        float4 a = s4[0], b = s4[1];
        v[0] = (short)f2b(a.x); v[1] = (short)f2b(a.y); v[2] = (short)f2b(a.z); v[3] = (short)f2b(a.w);
        v[4] = (short)f2b(b.x); v[5] = (short)f2b(b.y); v[6] = (short)f2b(b.z); v[7] = (short)f2b(b.w);
    } else {
#pragma unroll
        for (int j = 0; j < 8; j++) v[j] = (i + j < nSrc) ? (short)f2b(src[i + j]) : (short)0;
    }
    *(s16x8*)(dst + i) = v;
}

// ---------- weight transpose + convert ----------
__global__ __launch_bounds__(256) void wtrans_k(
    const float* __restrict__ W, u16* __restrict__ Wt, int K, int N, int rowOff)
{
    const int idx = blockIdx.x * 256 + threadIdx.x;
    if (idx >= K * N) return;
    const int n = idx / K, k = idx % K;
    Wt[idx] = f2b(W[(long)(k + rowOff) * N + n]);
}

extern "C" void kernel_launch(void* const* d_in, const int* in_sizes, int n_in,
                              void* d_out, int out_size, void* d_ws, size_t ws_size,
                              hipStream_t stream)
{
    const float* nodef = (const float*)d_in[0];
    const float* river = (const float*)d_in[1];
    const int*   edges = (const int*)d_in[2];
    const float* W1  = (const float*)d_in[3];
    const float* b1  = (const float*)d_in[4];
    const float* W2  = (const float*)d_in[5];
    const float* b2  = (const float*)d_in[6];
    const float* Wm1 = (const float*)d_in[7];
    const float* bm1 = (const float*)d_in[8];
    const float* Wm2 = (const float*)d_in[9];
    const float* bm2 = (const float*)d_in[10];
    float* out = (float*)d_out;
    (void)n_in; (void)out_size;

    const int M = 50000, Mpad = 50048, H = 512;
    const int nE = in_sizes[2] / 2;
    const size_t nElem = (size_t)Mpad * H;
    const size_t nOut  = (size_t)M * H;

    char* ws = (char*)d_ws;
    size_t off = 0;
    auto alloc = [&](size_t bytes) { void* p = ws + off; off += (bytes + 255) & ~(size_t)255; return p; };
    u16* feats16 = (u16*)alloc(nElem * 2);            // running features (bf16)
    u16* AB16    = (u16*)alloc(nElem * 4);            // [Mpad][1024]: A | B (nf16 early)
    u16* W1t     = (u16*)alloc(512 * 512 * 2);
    u16* W2t     = (u16*)alloc(512 * 512 * 2);
    u16* Wm1ct   = (u16*)alloc(1024 * 512 * 2);
    u16* Wm2t    = (u16*)alloc(512 * 512 * 2);
    int* deg     = (int*)alloc((size_t)Mpad * 4);
    int* rowptr  = (int*)alloc((size_t)Mpad * 4);
    int* cursor  = (int*)alloc((size_t)Mpad * 4);
    int* csr     = (int*)alloc((size_t)nE * 4);
    const size_t NEED_LEAN = off;                     // ~158 MB
    u16* Hg16ws  = (u16*)alloc(nElem * 2);
    const size_t NEED_FULL = off;                     // ~209 MB

    if (ws_size < NEED_LEAN) return;                  // tripwire: clean absmax fail
    const bool full = ws_size >= NEED_FULL;

    const dim3 ggrid(Mpad / 128, 4, 1);
    const dim3 ggridAB(Mpad / 128, 8, 1);
    const dim3 gblk(256, 1, 1);
    const int cvtBlocks = (int)(nElem / 8 / 256);

    // CSR build
    hipMemsetAsync(deg, 0, (size_t)Mpad * 4, stream);
    hipMemsetAsync(cursor, 0, (size_t)Mpad * 4, stream);
    deg_k<<<dim3((nE + 255) / 256), gblk, 0, stream>>>(edges, deg, nE);
    scan_k<<<dim3(1), gblk, 0, stream>>>(deg, rowptr, Mpad);
    scat_k<<<dim3((nE + 255) / 256), gblk, 0, stream>>>(edges, rowptr, cursor, csr, nE);

    // weights
    wtrans_k<<<dim3(1024), gblk, 0, stream>>>(W1,  W1t,             512, 512, 0);
    wtrans_k<<<dim3(1024), gblk, 0, stream>>>(W2,  W2t,             512, 512, 0);
    wtrans_k<<<dim3(1024), gblk, 0, stream>>>(Wm1, Wm1ct,           512, 512, 0);
    wtrans_k<<<dim3(1024), gblk, 0, stream>>>(Wm1, Wm1ct + 512*512, 512, 512, 512);
    wtrans_k<<<dim3(1024), gblk, 0, stream>>>(Wm2, Wm2t,            512, 512, 0);

    // node_features -> bf16 (flat [Mpad][512] in AB16's first half)
    cvt_pad_k<<<dim3(cvtBlocks), gblk, 0, stream>>>(nodef, AB16, (long)nOut, (long)nElem);

    // h1 = gelu(x @ W1 + b1 + river term); full: Hg16ws, lean: AB16 second half
    u16* h1 = full ? Hg16ws : (AB16 + nElem);
    gemm_k<F_BIAS | F_RANK3 | F_GELU | F_OUTH><<<ggrid, gblk, 0, stream>>>(
        AB16, W1t, nullptr, h1, nullptr, nullptr, b1, nullptr, nullptr, river, W1 + 512 * 512, M, 512);
    // feats = h1 @ W2 + b2
    if (full)
        gemm_k<F_BIAS | F_OUTF | F_OUTH><<<ggrid, gblk, 0, stream>>>(
            h1, W2t, out, feats16, nullptr, nullptr, b2, nullptr, nullptr, nullptr, nullptr, M, 512);
    else
        gemm_k<F_BIAS | F_OUTH><<<ggrid, gblk, 0, stream>>>(
            h1, W2t, nullptr, feats16, nullptr, nullptr, b2, nullptr, nullptr, nullptr, nullptr, M, 512);

    for (int r = 0; r < 3; r++) {
        // AB = feats @ [Wm1_top | Wm1_bot]
        gemm_k<F_OUTH><<<ggridAB, gblk, 0, stream>>>(
            feats16, Wm1ct, nullptr, AB16, nullptr, nullptr, nullptr, nullptr, nullptr, nullptr, nullptr, M, 1024);
        u16* Hg;
        if (full) {
            Hg = Hg16ws;
            gather_k<<<dim3(Mpad / 4), gblk, 0, stream>>>(rowptr, deg, csr, AB16, bm1, Hg, Mpad);
        } else {
            hipMemsetAsync(out, 0, nOut * 4, stream);
            edge_atomic_k<<<dim3((nE + 3) / 4), gblk, 0, stream>>>(edges, AB16, bm1, out, nE);
            cvt_pad_k<<<dim3(cvtBlocks), gblk, 0, stream>>>(out, AB16, (long)nOut, (long)nElem);
            Hg = AB16;
        }
        // feats = feats + Hg @ Wm2 + deg * bm2
        if (full) {
            if (r < 2)
                gemm_k<F_RESIDF | F_DEG | F_OUTF | F_OUTH><<<ggrid, gblk, 0, stream>>>(
                    Hg, Wm2t, out, feats16, out, nullptr, nullptr, bm2, deg, nullptr, nullptr, M, 512);
            else
                gemm_k<F_RESIDF | F_DEG | F_OUTF><<<ggrid, gblk, 0, stream>>>(
                    Hg, Wm2t, out, nullptr, out, nullptr, nullptr, bm2, deg, nullptr, nullptr, M, 512);
        } else {
            if (r < 2)
                gemm_k<F_RESIDH | F_DEG | F_OUTH><<<ggrid, gblk, 0, stream>>>(
                    Hg, Wm2t, nullptr, feats16, nullptr, feats16, nullptr, bm2, deg, nullptr, nullptr, M, 512);
            else
                gemm_k<F_RESIDH | F_DEG | F_OUTF><<<ggrid, gblk, 0, stream>>>(
                    Hg, Wm2t, out, nullptr, nullptr, feats16, nullptr, bm2, deg, nullptr, nullptr, M, 512);
        }
    }
}

// Round 4
// 836.459 us; speedup vs baseline: 8.4113x; 1.2524x over previous
//
#include <hip/hip_runtime.h>
#include <hip/hip_bf16.h>
#include <cstdint>

using u16 = unsigned short;
typedef short s16x8 __attribute__((ext_vector_type(8)));
typedef float f32x4 __attribute__((ext_vector_type(4)));

// ---------- helpers ----------
__device__ __forceinline__ float b2f(u16 b) {
    union { unsigned u; float f; } z; z.u = ((unsigned)b) << 16; return z.f;
}
__device__ __forceinline__ u16 f2b(float f) {
    union { float f; unsigned u; } z; z.f = f;
    return (u16)((z.u + 0x7fffu + ((z.u >> 16) & 1u)) >> 16);
}
__device__ __forceinline__ float gelu_f(float x) {
    return 0.5f * x * (1.0f + erff(x * 0.70710678118654752440f));
}
__device__ __forceinline__ void gl2lds16(const void* g, void* l) {
    __builtin_amdgcn_global_load_lds(
        (const __attribute__((address_space(1))) void*)g,
        (__attribute__((address_space(3))) void*)l, 16, 0, 0);
}

enum { F_BIAS = 1, F_GELU = 2, F_RANK3 = 4, F_RESIDH = 8,
       F_DEG = 16, F_OUTF = 32, F_OUTH = 64 };

// ---------- GEMM: C = epilogue(A_bf16[M x 512] @ Bt_bf16[N x 512]^T) ----------
// Bt stored N-major. 128x128 tile, 4 waves (2x2), BK=32, global_load_lds x16.
// srcH==Ch aliasing is safe: each element is read+written by exactly one thread.
template<int EPI>
__global__ __launch_bounds__(256, 4) void gemm_k(
    const u16* __restrict__ A, const u16* __restrict__ Bt,
    float* __restrict__ Cf, u16* __restrict__ Ch,
    const u16* __restrict__ srcH,
    const float* __restrict__ bias, const float* __restrict__ bias2,
    const int* __restrict__ deg, const float* __restrict__ river,
    const float* __restrict__ w1tail, int Mreal, int ldh)
{
    __shared__ __align__(16) u16 As[128 * 32];
    __shared__ __align__(16) u16 Bs[128 * 32];

    const int tid  = threadIdx.x;
    const int lane = tid & 63;
    const int wid  = tid >> 6;
    const int wr   = wid >> 1;
    const int wc   = wid & 1;
    const int fr   = lane & 15;
    const int fq   = lane >> 4;

    const long arow = (long)blockIdx.x * 128 + (wid << 4) + (lane >> 2);
    const long brow = (long)blockIdx.y * 128 + (wid << 4) + (lane >> 2);
    const int  kofs = (lane & 3) << 3;
    u16* asw = As + (wid << 9);
    u16* bsw = Bs + (wid << 9);

    f32x4 acc[4][4];
#pragma unroll
    for (int m = 0; m < 4; m++)
#pragma unroll
        for (int n = 0; n < 4; n++) { f32x4 z = {0.f, 0.f, 0.f, 0.f}; acc[m][n] = z; }

    for (int kt = 0; kt < 512; kt += 32) {
        gl2lds16(A  + arow * 512 + kt + kofs,        asw);
        gl2lds16(A  + (arow + 64) * 512 + kt + kofs, asw + 2048);
        gl2lds16(Bt + brow * 512 + kt + kofs,        bsw);
        gl2lds16(Bt + (brow + 64) * 512 + kt + kofs, bsw + 2048);
        __syncthreads();

        s16x8 af[4], bf[4];
#pragma unroll
        for (int m = 0; m < 4; m++)
            af[m] = *(const s16x8*)(As + (((wr << 6) + (m << 4) + fr) << 5) + (fq << 3));
#pragma unroll
        for (int n = 0; n < 4; n++)
            bf[n] = *(const s16x8*)(Bs + (((wc << 6) + (n << 4) + fr) << 5) + (fq << 3));
#pragma unroll
        for (int m = 0; m < 4; m++)
#pragma unroll
            for (int n = 0; n < 4; n++)
                acc[m][n] = __builtin_amdgcn_mfma_f32_16x16x32_bf16(af[m], bf[n], acc[m][n], 0, 0, 0);
        __syncthreads();
    }

    const int colbase = (blockIdx.y << 7) + (wc << 6);
#pragma unroll
    for (int m = 0; m < 4; m++) {
        const int row0 = (blockIdx.x << 7) + (wr << 6) + (m << 4) + (fq << 2);
#pragma unroll
        for (int r = 0; r < 4; r++) {
            const int rr = row0 + r;
            const bool real = rr < Mreal;
            float rv0 = 0.f, rv1 = 0.f, rv2 = 0.f;
            if constexpr (EPI & F_RANK3) {
                if (real) { rv0 = river[rr * 3]; rv1 = river[rr * 3 + 1]; rv2 = river[rr * 3 + 2]; }
            }
            float dg = 0.f;
            if constexpr (EPI & F_DEG) { if (real) dg = (float)deg[rr]; }
#pragma unroll
            for (int n = 0; n < 4; n++) {
                const int col = colbase + (n << 4) + fr;
                float v = acc[m][n][r];
                if constexpr (EPI & F_BIAS)   v += bias[col];
                if constexpr (EPI & F_RANK3)  v += rv0 * w1tail[col] + rv1 * w1tail[512 + col] + rv2 * w1tail[1024 + col];
                if constexpr (EPI & F_GELU)   v = gelu_f(v);
                if constexpr (EPI & F_RESIDH) v += b2f(srcH[(long)rr * 512 + col]);
                if constexpr (EPI & F_DEG)    v += dg * bias2[col];
                if constexpr (EPI & F_OUTF)   { if (real) Cf[(long)rr * 512 + col] = v; }
                if constexpr (EPI & F_OUTH)   Ch[(long)rr * ldh + col] = f2b(v);
            }
        }
    }
}

// ---------- CSR build ----------
__global__ __launch_bounds__(256) void deg_k(const int* __restrict__ ed, int* __restrict__ deg, int nE)
{
    const int e = blockIdx.x * 256 + threadIdx.x;
    if (e < nE) atomicAdd(&deg[ed[2 * e + 1]], 1);
}

__global__ __launch_bounds__(256) void scan_k(const int* __restrict__ deg, int* __restrict__ rowptr, int n)
{
    __shared__ int part[256];
    const int tid = threadIdx.x;
    const int per = (n + 255) / 256;
    const int start = tid * per;
    int sum = 0;
    for (int i = start; i < start + per && i < n; i++) sum += deg[i];
    part[tid] = sum;
    __syncthreads();
    if (tid == 0) {
        int acc = 0;
        for (int i = 0; i < 256; i++) { int v = part[i]; part[i] = acc; acc += v; }
    }
    __syncthreads();
    int acc = part[tid];
    for (int i = start; i < start + per && i < n; i++) { rowptr[i] = acc; acc += deg[i]; }
}

__global__ __launch_bounds__(256) void scat_k(
    const int* __restrict__ ed, const int* __restrict__ rowptr,
    int* __restrict__ cursor, int* __restrict__ csr, int nE)
{
    const int e = blockIdx.x * 256 + threadIdx.x;
    if (e >= nE) return;
    const int t = ed[2 * e + 1];
    const int p = atomicAdd(&cursor[t], 1);
    csr[rowptr[t] + p] = ed[2 * e];
}

// ---------- gather: Hg[t] = bf16( sum_{s in in(t)} gelu(A[s] + B[t] + bm1) ) ----------
// AB layout [Mpad][1024]: A at row*1024, B at row*1024+512. One wave per node.
__global__ __launch_bounds__(256) void gather_k(
    const int* __restrict__ rowptr, const int* __restrict__ degv,
    const int* __restrict__ csr, const u16* __restrict__ AB,
    const float* __restrict__ bm1, u16* __restrict__ Hg, int nNodes)
{
    const int t = (blockIdx.x << 2) + (threadIdx.x >> 6);
    if (t >= nNodes) return;
    const int lane = threadIdx.x & 63;
    const int c = lane << 3;
    float acc[8] = {0.f, 0.f, 0.f, 0.f, 0.f, 0.f, 0.f, 0.f};
    const int d = degv[t];
    if (d > 0) {
        s16x8 bv = *(const s16x8*)(AB + (long)t * 1024 + 512 + c);
        const float4* bmv = (const float4*)(bm1 + c);
        float4 q0 = bmv[0], q1 = bmv[1];
        float base[8] = { q0.x, q0.y, q0.z, q0.w, q1.x, q1.y, q1.z, q1.w };
#pragma unroll
        for (int j = 0; j < 8; j++) base[j] += b2f((u16)bv[j]);
        const int p0 = rowptr[t];
        for (int i = 0; i < d; i++) {
            const int s = csr[p0 + i];
            s16x8 av = *(const s16x8*)(AB + (long)s * 1024 + c);
#pragma unroll
            for (int j = 0; j < 8; j++) acc[j] += gelu_f(b2f((u16)av[j]) + base[j]);
        }
    }
    s16x8 o;
#pragma unroll
    for (int j = 0; j < 8; j++) o[j] = (short)f2b(acc[j]);
    *(s16x8*)(Hg + (long)t * 512 + c) = o;
}

// ---------- f32 -> bf16 (flat, region beyond nSrc zero-filled) ----------
__global__ __launch_bounds__(256) void cvt_pad_k(
    const float* __restrict__ src, u16* __restrict__ dst, long nSrc, long nTot)
{
    const long i = ((long)blockIdx.x * 256 + threadIdx.x) * 8;
    if (i >= nTot) return;
    s16x8 v;
    if (i + 8 <= nSrc) {
        const float4* s4 = (const float4*)(src + i);
        float4 a = s4[0], b = s4[1];
        v[0] = (short)f2b(a.x); v[1] = (short)f2b(a.y); v[2] = (short)f2b(a.z); v[3] = (short)f2b(a.w);
        v[4] = (short)f2b(b.x); v[5] = (short)f2b(b.y); v[6] = (short)f2b(b.z); v[7] = (short)f2b(b.w);
    } else {
#pragma unroll
        for (int j = 0; j < 8; j++) v[j] = (i + j < nSrc) ? (short)f2b(src[i + j]) : (short)0;
    }
    *(s16x8*)(dst + i) = v;
}

// ---------- weight transpose + convert: Wt[n*K+k] = bf16(W[(k+off)*N + n]) ----------
__global__ __launch_bounds__(256) void wtrans_k(
    const float* __restrict__ W, u16* __restrict__ Wt, int K, int N, int rowOff)
{
    const int idx = blockIdx.x * 256 + threadIdx.x;
    if (idx >= K * N) return;
    const int n = idx / K, k = idx % K;
    Wt[idx] = f2b(W[(long)(k + rowOff) * N + n]);
}

extern "C" void kernel_launch(void* const* d_in, const int* in_sizes, int n_in,
                              void* d_out, int out_size, void* d_ws, size_t ws_size,
                              hipStream_t stream)
{
    const float* nodef = (const float*)d_in[0];
    const float* river = (const float*)d_in[1];
    const int*   edges = (const int*)d_in[2];
    const float* W1  = (const float*)d_in[3];
    const float* b1  = (const float*)d_in[4];
    const float* W2  = (const float*)d_in[5];
    const float* b2  = (const float*)d_in[6];
    const float* Wm1 = (const float*)d_in[7];
    const float* bm1 = (const float*)d_in[8];
    const float* Wm2 = (const float*)d_in[9];
    const float* bm2 = (const float*)d_in[10];
    float* out = (float*)d_out;
    (void)n_in; (void)out_size;

    const int M = 50000, Mpad = 50048, H = 512;
    const int nE = in_sizes[2] / 2;
    const size_t nElem = (size_t)Mpad * H;
    const size_t nOut  = (size_t)M * H;

    char* ws = (char*)d_ws;
    size_t off = 0;
    auto alloc = [&](size_t bytes) { void* p = ws + off; off += (bytes + 255) & ~(size_t)255; return p; };
    u16* feats16 = (u16*)alloc(nElem * 2);            // running features (bf16, residual carrier)
    u16* AB16    = (u16*)alloc(nElem * 4);            // [Mpad][1024]: A | B (nf16 early)
    u16* Hg16    = (u16*)alloc(nElem * 2);            // gather output / h1
    u16* W1t     = (u16*)alloc(512 * 512 * 2);
    u16* W2t     = (u16*)alloc(512 * 512 * 2);
    u16* Wm1ct   = (u16*)alloc(1024 * 512 * 2);
    u16* Wm2t    = (u16*)alloc(512 * 512 * 2);
    int* deg     = (int*)alloc((size_t)Mpad * 4);
    int* rowptr  = (int*)alloc((size_t)Mpad * 4);
    int* cursor  = (int*)alloc((size_t)Mpad * 4);
    int* csr     = (int*)alloc((size_t)nE * 4);
    const size_t NEED = off;                          // ~209 MB (confirmed fits in R3)

    if (ws_size < NEED) return;                       // tripwire: clean absmax fail

    const dim3 ggrid(Mpad / 128, 4, 1);
    const dim3 ggridAB(Mpad / 128, 8, 1);
    const dim3 gblk(256, 1, 1);
    const int cvtBlocks = (int)(nElem / 8 / 256);

    // CSR build (edges fixed; rebuilt every call for determinism)
    hipMemsetAsync(deg, 0, (size_t)Mpad * 4, stream);
    hipMemsetAsync(cursor, 0, (size_t)Mpad * 4, stream);
    deg_k<<<dim3((nE + 255) / 256), gblk, 0, stream>>>(edges, deg, nE);
    scan_k<<<dim3(1), gblk, 0, stream>>>(deg, rowptr, Mpad);
    scat_k<<<dim3((nE + 255) / 256), gblk, 0, stream>>>(edges, rowptr, cursor, csr, nE);

    // weights -> transposed bf16
    wtrans_k<<<dim3(1024), gblk, 0, stream>>>(W1,  W1t,             512, 512, 0);
    wtrans_k<<<dim3(1024), gblk, 0, stream>>>(W2,  W2t,             512, 512, 0);
    wtrans_k<<<dim3(1024), gblk, 0, stream>>>(Wm1, Wm1ct,           512, 512, 0);
    wtrans_k<<<dim3(1024), gblk, 0, stream>>>(Wm1, Wm1ct + 512*512, 512, 512, 512);
    wtrans_k<<<dim3(1024), gblk, 0, stream>>>(Wm2, Wm2t,            512, 512, 0);

    // node_features -> bf16 (flat [Mpad][512] in AB16 first half, padded rows zero)
    cvt_pad_k<<<dim3(cvtBlocks), gblk, 0, stream>>>(nodef, AB16, (long)nOut, (long)nElem);

    // h1 = gelu(x @ W1 + b1 + river @ W1tail) -> Hg16
    gemm_k<F_BIAS | F_RANK3 | F_GELU | F_OUTH><<<ggrid, gblk, 0, stream>>>(
        AB16, W1t, nullptr, Hg16, nullptr, b1, nullptr, nullptr, river, W1 + 512 * 512, M, 512);
    // feats16 = h1 @ W2 + b2  (bf16 only)
    gemm_k<F_BIAS | F_OUTH><<<ggrid, gblk, 0, stream>>>(
        Hg16, W2t, nullptr, feats16, nullptr, b2, nullptr, nullptr, nullptr, nullptr, M, 512);

    for (int r = 0; r < 3; r++) {
        // AB = feats @ [Wm1_top | Wm1_bot]  (N=1024 combined)
        gemm_k<F_OUTH><<<ggridAB, gblk, 0, stream>>>(
            feats16, Wm1ct, nullptr, AB16, nullptr, nullptr, nullptr, nullptr, nullptr, nullptr, M, 1024);
        // Hg[t] = sum_in gelu(A[s] + B[t] + bm1)
        gather_k<<<dim3(Mpad / 4), gblk, 0, stream>>>(rowptr, deg, csr, AB16, bm1, Hg16, Mpad);
        // feats = feats + Hg @ Wm2 + deg * bm2
        if (r < 2)
            gemm_k<F_RESIDH | F_DEG | F_OUTH><<<ggrid, gblk, 0, stream>>>(
                Hg16, Wm2t, nullptr, feats16, feats16, nullptr, bm2, deg, nullptr, nullptr, M, 512);
        else
            gemm_k<F_RESIDH | F_DEG | F_OUTF><<<ggrid, gblk, 0, stream>>>(
                Hg16, Wm2t, out, nullptr, feats16, nullptr, bm2, deg, nullptr, nullptr, M, 512);
    }
}

// Round 5
// 819.177 us; speedup vs baseline: 8.5888x; 1.0211x over previous
//
#include <hip/hip_runtime.h>
#include <hip/hip_bf16.h>
#include <cstdint>

using u16 = unsigned short;
typedef short s16x8 __attribute__((ext_vector_type(8)));
typedef float f32x4 __attribute__((ext_vector_type(4)));

// ---------- helpers ----------
__device__ __forceinline__ float b2f(u16 b) {
    union { unsigned u; float f; } z; z.u = ((unsigned)b) << 16; return z.f;
}
__device__ __forceinline__ u16 f2b(float f) {
    union { float f; unsigned u; } z; z.f = f;
    return (u16)((z.u + 0x7fffu + ((z.u >> 16) & 1u)) >> 16);
}
__device__ __forceinline__ float gelu_f(float x) {
    return 0.5f * x * (1.0f + erff(x * 0.70710678118654752440f));
}
__device__ __forceinline__ void gl2lds16(const void* g, void* l) {
    __builtin_amdgcn_global_load_lds(
        (const __attribute__((address_space(1))) void*)g,
        (__attribute__((address_space(3))) void*)l, 16, 0, 0);
}

enum { F_BIAS = 1, F_GELU = 2, F_RANK3 = 4, F_RESIDH = 8,
       F_DEG = 16, F_OUTF = 32, F_OUTH = 64 };

// ---------- GEMM: C = epilogue(A_bf16[M x 512] @ Bt_bf16[N x 512]^T) ----------
// Grid is (N/128, M/128) with the COLUMN dim fastest-varying: consecutive
// blocks share one A row-tile, so it is HBM-fetched once and L2-served for
// the rest (R4 showed 4-8x A re-fetch with row-fastest order).
// Bt stored N-major. 128x128 tile, 4 waves (2x2), BK=32, global_load_lds x16.
// srcH==Ch aliasing is safe: each element is read+written by exactly one thread.
template<int EPI>
__global__ __launch_bounds__(256, 4) void gemm_k(
    const u16* __restrict__ A, const u16* __restrict__ Bt,
    float* __restrict__ Cf, u16* __restrict__ Ch,
    const u16* __restrict__ srcH,
    const float* __restrict__ bias, const float* __restrict__ bias2,
    const int* __restrict__ deg, const float* __restrict__ river,
    const float* __restrict__ w1tail, int Mreal, int ldh)
{
    __shared__ __align__(16) u16 As[128 * 32];
    __shared__ __align__(16) u16 Bs[128 * 32];

    const int rowblk = blockIdx.y;   // M tile
    const int colblk = blockIdx.x;   // N tile (fastest-varying in dispatch)

    const int tid  = threadIdx.x;
    const int lane = tid & 63;
    const int wid  = tid >> 6;
    const int wr   = wid >> 1;
    const int wc   = wid & 1;
    const int fr   = lane & 15;
    const int fq   = lane >> 4;

    const long arow = (long)rowblk * 128 + (wid << 4) + (lane >> 2);
    const long brow = (long)colblk * 128 + (wid << 4) + (lane >> 2);
    const int  kofs = (lane & 3) << 3;
    u16* asw = As + (wid << 9);
    u16* bsw = Bs + (wid << 9);

    f32x4 acc[4][4];
#pragma unroll
    for (int m = 0; m < 4; m++)
#pragma unroll
        for (int n = 0; n < 4; n++) { f32x4 z = {0.f, 0.f, 0.f, 0.f}; acc[m][n] = z; }

    for (int kt = 0; kt < 512; kt += 32) {
        gl2lds16(A  + arow * 512 + kt + kofs,        asw);
        gl2lds16(A  + (arow + 64) * 512 + kt + kofs, asw + 2048);
        gl2lds16(Bt + brow * 512 + kt + kofs,        bsw);
        gl2lds16(Bt + (brow + 64) * 512 + kt + kofs, bsw + 2048);
        __syncthreads();

        s16x8 af[4], bf[4];
#pragma unroll
        for (int m = 0; m < 4; m++)
            af[m] = *(const s16x8*)(As + (((wr << 6) + (m << 4) + fr) << 5) + (fq << 3));
#pragma unroll
        for (int n = 0; n < 4; n++)
            bf[n] = *(const s16x8*)(Bs + (((wc << 6) + (n << 4) + fr) << 5) + (fq << 3));
#pragma unroll
        for (int m = 0; m < 4; m++)
#pragma unroll
            for (int n = 0; n < 4; n++)
                acc[m][n] = __builtin_amdgcn_mfma_f32_16x16x32_bf16(af[m], bf[n], acc[m][n], 0, 0, 0);
        __syncthreads();
    }

    const int colbase = (colblk << 7) + (wc << 6);
#pragma unroll
    for (int m = 0; m < 4; m++) {
        const int row0 = (rowblk << 7) + (wr << 6) + (m << 4) + (fq << 2);
#pragma unroll
        for (int r = 0; r < 4; r++) {
            const int rr = row0 + r;
            const bool real = rr < Mreal;
            float rv0 = 0.f, rv1 = 0.f, rv2 = 0.f;
            if constexpr (EPI & F_RANK3) {
                if (real) { rv0 = river[rr * 3]; rv1 = river[rr * 3 + 1]; rv2 = river[rr * 3 + 2]; }
            }
            float dg = 0.f;
            if constexpr (EPI & F_DEG) { if (real) dg = (float)deg[rr]; }
#pragma unroll
            for (int n = 0; n < 4; n++) {
                const int col = colbase + (n << 4) + fr;
                float v = acc[m][n][r];
                if constexpr (EPI & F_BIAS)   v += bias[col];
                if constexpr (EPI & F_RANK3)  v += rv0 * w1tail[col] + rv1 * w1tail[512 + col] + rv2 * w1tail[1024 + col];
                if constexpr (EPI & F_GELU)   v = gelu_f(v);
                if constexpr (EPI & F_RESIDH) v += b2f(srcH[(long)rr * 512 + col]);
                if constexpr (EPI & F_DEG)    v += dg * bias2[col];
                if constexpr (EPI & F_OUTF)   { if (real) Cf[(long)rr * 512 + col] = v; }
                if constexpr (EPI & F_OUTH)   Ch[(long)rr * ldh + col] = f2b(v);
            }
        }
    }
}

// ---------- CSR build ----------
__global__ __launch_bounds__(256) void deg_k(const int* __restrict__ ed, int* __restrict__ deg, int nE)
{
    const int e = blockIdx.x * 256 + threadIdx.x;
    if (e < nE) atomicAdd(&deg[ed[2 * e + 1]], 1);
}

__global__ __launch_bounds__(256) void scan_k(const int* __restrict__ deg, int* __restrict__ rowptr, int n)
{
    __shared__ int part[256];
    const int tid = threadIdx.x;
    const int per = (n + 255) / 256;
    const int start = tid * per;
    int sum = 0;
    for (int i = start; i < start + per && i < n; i++) sum += deg[i];
    part[tid] = sum;
    __syncthreads();
    if (tid == 0) {
        int acc = 0;
        for (int i = 0; i < 256; i++) { int v = part[i]; part[i] = acc; acc += v; }
    }
    __syncthreads();
    int acc = part[tid];
    for (int i = start; i < start + per && i < n; i++) { rowptr[i] = acc; acc += deg[i]; }
}

__global__ __launch_bounds__(256) void scat_k(
    const int* __restrict__ ed, const int* __restrict__ rowptr,
    int* __restrict__ cursor, int* __restrict__ csr, int nE)
{
    const int e = blockIdx.x * 256 + threadIdx.x;
    if (e >= nE) return;
    const int t = ed[2 * e + 1];
    const int p = atomicAdd(&cursor[t], 1);
    csr[rowptr[t] + p] = ed[2 * e];
}

// ---------- gather: Hg[t] = bf16( sum_{s in in(t)} gelu(A[s] + B[t] + bm1) ) ----------
// AB layout [Mpad][1024]: A at row*1024, B at row*1024+512. One wave per node.
__global__ __launch_bounds__(256) void gather_k(
    const int* __restrict__ rowptr, const int* __restrict__ degv,
    const int* __restrict__ csr, const u16* __restrict__ AB,
    const float* __restrict__ bm1, u16* __restrict__ Hg, int nNodes)
{
    const int t = (blockIdx.x << 2) + (threadIdx.x >> 6);
    if (t >= nNodes) return;
    const int lane = threadIdx.x & 63;
    const int c = lane << 3;
    float acc[8] = {0.f, 0.f, 0.f, 0.f, 0.f, 0.f, 0.f, 0.f};
    const int d = degv[t];
    if (d > 0) {
        s16x8 bv = *(const s16x8*)(AB + (long)t * 1024 + 512 + c);
        const float4* bmv = (const float4*)(bm1 + c);
        float4 q0 = bmv[0], q1 = bmv[1];
        float base[8] = { q0.x, q0.y, q0.z, q0.w, q1.x, q1.y, q1.z, q1.w };
#pragma unroll
        for (int j = 0; j < 8; j++) base[j] += b2f((u16)bv[j]);
        const int p0 = rowptr[t];
        for (int i = 0; i < d; i++) {
            const int s = csr[p0 + i];
            s16x8 av = *(const s16x8*)(AB + (long)s * 1024 + c);
#pragma unroll
            for (int j = 0; j < 8; j++) acc[j] += gelu_f(b2f((u16)av[j]) + base[j]);
        }
    }
    s16x8 o;
#pragma unroll
    for (int j = 0; j < 8; j++) o[j] = (short)f2b(acc[j]);
    *(s16x8*)(Hg + (long)t * 512 + c) = o;
}

// ---------- f32 -> bf16 (flat, region beyond nSrc zero-filled) ----------
__global__ __launch_bounds__(256) void cvt_pad_k(
    const float* __restrict__ src, u16* __restrict__ dst, long nSrc, long nTot)
{
    const long i = ((long)blockIdx.x * 256 + threadIdx.x) * 8;
    if (i >= nTot) return;
    s16x8 v;
    if (i + 8 <= nSrc) {
        const float4* s4 = (const float4*)(src + i);
        float4 a = s4[0], b = s4[1];
        v[0] = (short)f2b(a.x); v[1] = (short)f2b(a.y); v[2] = (short)f2b(a.z); v[3] = (short)f2b(a.w);
        v[4] = (short)f2b(b.x); v[5] = (short)f2b(b.y); v[6] = (short)f2b(b.z); v[7] = (short)f2b(b.w);
    } else {
#pragma unroll
        for (int j = 0; j < 8; j++) v[j] = (i + j < nSrc) ? (short)f2b(src[i + j]) : (short)0;
    }
    *(s16x8*)(dst + i) = v;
}

// ---------- weight transpose + convert: Wt[n*K+k] = bf16(W[(k+off)*N + n]) ----------
__global__ __launch_bounds__(256) void wtrans_k(
    const float* __restrict__ W, u16* __restrict__ Wt, int K, int N, int rowOff)
{
    const int idx = blockIdx.x * 256 + threadIdx.x;
    if (idx >= K * N) return;
    const int n = idx / K, k = idx % K;
    Wt[idx] = f2b(W[(long)(k + rowOff) * N + n]);
}

extern "C" void kernel_launch(void* const* d_in, const int* in_sizes, int n_in,
                              void* d_out, int out_size, void* d_ws, size_t ws_size,
                              hipStream_t stream)
{
    const float* nodef = (const float*)d_in[0];
    const float* river = (const float*)d_in[1];
    const int*   edges = (const int*)d_in[2];
    const float* W1  = (const float*)d_in[3];
    const float* b1  = (const float*)d_in[4];
    const float* W2  = (const float*)d_in[5];
    const float* b2  = (const float*)d_in[6];
    const float* Wm1 = (const float*)d_in[7];
    const float* bm1 = (const float*)d_in[8];
    const float* Wm2 = (const float*)d_in[9];
    const float* bm2 = (const float*)d_in[10];
    float* out = (float*)d_out;
    (void)n_in; (void)out_size;

    const int M = 50000, Mpad = 50048, H = 512;
    const int nE = in_sizes[2] / 2;
    const size_t nElem = (size_t)Mpad * H;
    const size_t nOut  = (size_t)M * H;

    char* ws = (char*)d_ws;
    size_t off = 0;
    auto alloc = [&](size_t bytes) { void* p = ws + off; off += (bytes + 255) & ~(size_t)255; return p; };
    u16* feats16 = (u16*)alloc(nElem * 2);            // running features (bf16, residual carrier)
    u16* AB16    = (u16*)alloc(nElem * 4);            // [Mpad][1024]: A | B (nf16 early)
    u16* Hg16    = (u16*)alloc(nElem * 2);            // gather output / h1
    u16* W1t     = (u16*)alloc(512 * 512 * 2);
    u16* W2t     = (u16*)alloc(512 * 512 * 2);
    u16* Wm1ct   = (u16*)alloc(1024 * 512 * 2);
    u16* Wm2t    = (u16*)alloc(512 * 512 * 2);
    int* deg     = (int*)alloc((size_t)Mpad * 4);
    int* rowptr  = (int*)alloc((size_t)Mpad * 4);
    int* cursor  = (int*)alloc((size_t)Mpad * 4);
    int* csr     = (int*)alloc((size_t)nE * 4);
    const size_t NEED = off;                          // ~209 MB (confirmed fits)

    if (ws_size < NEED) return;                       // tripwire: clean absmax fail

    // column-fastest grids: (N/128, M/128)
    const dim3 ggrid(4, Mpad / 128, 1);
    const dim3 ggridAB(8, Mpad / 128, 1);
    const dim3 gblk(256, 1, 1);
    const int cvtBlocks = (int)(nElem / 8 / 256);

    // CSR build (edges fixed; rebuilt every call for determinism)
    hipMemsetAsync(deg, 0, (size_t)Mpad * 4, stream);
    hipMemsetAsync(cursor, 0, (size_t)Mpad * 4, stream);
    deg_k<<<dim3((nE + 255) / 256), gblk, 0, stream>>>(edges, deg, nE);
    scan_k<<<dim3(1), gblk, 0, stream>>>(deg, rowptr, Mpad);
    scat_k<<<dim3((nE + 255) / 256), gblk, 0, stream>>>(edges, rowptr, cursor, csr, nE);

    // weights -> transposed bf16
    wtrans_k<<<dim3(1024), gblk, 0, stream>>>(W1,  W1t,             512, 512, 0);
    wtrans_k<<<dim3(1024), gblk, 0, stream>>>(W2,  W2t,             512, 512, 0);
    wtrans_k<<<dim3(1024), gblk, 0, stream>>>(Wm1, Wm1ct,           512, 512, 0);
    wtrans_k<<<dim3(1024), gblk, 0, stream>>>(Wm1, Wm1ct + 512*512, 512, 512, 512);
    wtrans_k<<<dim3(1024), gblk, 0, stream>>>(Wm2, Wm2t,            512, 512, 0);

    // node_features -> bf16 (flat [Mpad][512] in AB16 first half, padded rows zero)
    cvt_pad_k<<<dim3(cvtBlocks), gblk, 0, stream>>>(nodef, AB16, (long)nOut, (long)nElem);

    // h1 = gelu(x @ W1 + b1 + river @ W1tail) -> Hg16
    gemm_k<F_BIAS | F_RANK3 | F_GELU | F_OUTH><<<ggrid, gblk, 0, stream>>>(
        AB16, W1t, nullptr, Hg16, nullptr, b1, nullptr, nullptr, river, W1 + 512 * 512, M, 512);
    // feats16 = h1 @ W2 + b2  (bf16 only)
    gemm_k<F_BIAS | F_OUTH><<<ggrid, gblk, 0, stream>>>(
        Hg16, W2t, nullptr, feats16, nullptr, b2, nullptr, nullptr, nullptr, nullptr, M, 512);

    for (int r = 0; r < 3; r++) {
        // AB = feats @ [Wm1_top | Wm1_bot]  (N=1024 combined)
        gemm_k<F_OUTH><<<ggridAB, gblk, 0, stream>>>(
            feats16, Wm1ct, nullptr, AB16, nullptr, nullptr, nullptr, nullptr, nullptr, nullptr, M, 1024);
        // Hg[t] = sum_in gelu(A[s] + B[t] + bm1)
        gather_k<<<dim3(Mpad / 4), gblk, 0, stream>>>(rowptr, deg, csr, AB16, bm1, Hg16, Mpad);
        // feats = feats + Hg @ Wm2 + deg * bm2
        if (r < 2)
            gemm_k<F_RESIDH | F_DEG | F_OUTH><<<ggrid, gblk, 0, stream>>>(
                Hg16, Wm2t, nullptr, feats16, feats16, nullptr, bm2, deg, nullptr, nullptr, M, 512);
        else
            gemm_k<F_RESIDH | F_DEG | F_OUTF><<<ggrid, gblk, 0, stream>>>(
                Hg16, Wm2t, out, nullptr, feats16, nullptr, bm2, deg, nullptr, nullptr, M, 512);
    }
}

// Round 6
// 742.476 us; speedup vs baseline: 9.4760x; 1.1033x over previous
//
#include <hip/hip_runtime.h>
#include <hip/hip_bf16.h>
#include <cstdint>

using u16 = unsigned short;
typedef short s16x8 __attribute__((ext_vector_type(8)));
typedef float f32x4 __attribute__((ext_vector_type(4)));

// ---------- helpers ----------
__device__ __forceinline__ float b2f(u16 b) {
    union { unsigned u; float f; } z; z.u = ((unsigned)b) << 16; return z.f;
}
__device__ __forceinline__ u16 f2b(float f) {
    union { float f; unsigned u; } z; z.f = f;
    return (u16)((z.u + 0x7fffu + ((z.u >> 16) & 1u)) >> 16);
}
__device__ __forceinline__ float gelu_f(float x) {
    return 0.5f * x * (1.0f + erff(x * 0.70710678118654752440f));
}
__device__ __forceinline__ void gl2lds16(const void* g, void* l) {
    __builtin_amdgcn_global_load_lds(
        (const __attribute__((address_space(1))) void*)g,
        (__attribute__((address_space(3))) void*)l, 16, 0, 0);
}

enum { F_BIAS = 1, F_GELU = 2, F_RANK3 = 4, F_RESIDH = 8,
       F_DEG = 16, F_OUTF = 32, F_OUTH = 64 };

// ---------- GEMM: C = epilogue(A_bf16[M x 512] @ Bt_bf16[N x 512]^T) ----------
// Grid is (N/128, M/128), column-fastest so blocks sharing an A row-tile are
// dispatched together (A re-reads served by L2/L3, not HBM).
template<int EPI>
__global__ __launch_bounds__(256, 4) void gemm_k(
    const u16* __restrict__ A, const u16* __restrict__ Bt,
    float* __restrict__ Cf, u16* __restrict__ Ch,
    const u16* __restrict__ srcH,
    const float* __restrict__ bias, const float* __restrict__ bias2,
    const int* __restrict__ deg, const float* __restrict__ river,
    const float* __restrict__ w1tail, int Mreal, int ldh)
{
    __shared__ __align__(16) u16 As[128 * 32];
    __shared__ __align__(16) u16 Bs[128 * 32];

    const int rowblk = blockIdx.y;
    const int colblk = blockIdx.x;

    const int tid  = threadIdx.x;
    const int lane = tid & 63;
    const int wid  = tid >> 6;
    const int wr   = wid >> 1;
    const int wc   = wid & 1;
    const int fr   = lane & 15;
    const int fq   = lane >> 4;

    const long arow = (long)rowblk * 128 + (wid << 4) + (lane >> 2);
    const long brow = (long)colblk * 128 + (wid << 4) + (lane >> 2);
    const int  kofs = (lane & 3) << 3;
    u16* asw = As + (wid << 9);
    u16* bsw = Bs + (wid << 9);

    f32x4 acc[4][4];
#pragma unroll
    for (int m = 0; m < 4; m++)
#pragma unroll
        for (int n = 0; n < 4; n++) { f32x4 z = {0.f, 0.f, 0.f, 0.f}; acc[m][n] = z; }

    for (int kt = 0; kt < 512; kt += 32) {
        gl2lds16(A  + arow * 512 + kt + kofs,        asw);
        gl2lds16(A  + (arow + 64) * 512 + kt + kofs, asw + 2048);
        gl2lds16(Bt + brow * 512 + kt + kofs,        bsw);
        gl2lds16(Bt + (brow + 64) * 512 + kt + kofs, bsw + 2048);
        __syncthreads();

        s16x8 af[4], bf[4];
#pragma unroll
        for (int m = 0; m < 4; m++)
            af[m] = *(const s16x8*)(As + (((wr << 6) + (m << 4) + fr) << 5) + (fq << 3));
#pragma unroll
        for (int n = 0; n < 4; n++)
            bf[n] = *(const s16x8*)(Bs + (((wc << 6) + (n << 4) + fr) << 5) + (fq << 3));
#pragma unroll
        for (int m = 0; m < 4; m++)
#pragma unroll
            for (int n = 0; n < 4; n++)
                acc[m][n] = __builtin_amdgcn_mfma_f32_16x16x32_bf16(af[m], bf[n], acc[m][n], 0, 0, 0);
        __syncthreads();
    }

    const int colbase = (colblk << 7) + (wc << 6);
#pragma unroll
    for (int m = 0; m < 4; m++) {
        const int row0 = (rowblk << 7) + (wr << 6) + (m << 4) + (fq << 2);
#pragma unroll
        for (int r = 0; r < 4; r++) {
            const int rr = row0 + r;
            const bool real = rr < Mreal;
            float rv0 = 0.f, rv1 = 0.f, rv2 = 0.f;
            if constexpr (EPI & F_RANK3) {
                if (real) { rv0 = river[rr * 3]; rv1 = river[rr * 3 + 1]; rv2 = river[rr * 3 + 2]; }
            }
            float dg = 0.f;
            if constexpr (EPI & F_DEG) { if (real) dg = (float)deg[rr]; }
#pragma unroll
            for (int n = 0; n < 4; n++) {
                const int col = colbase + (n << 4) + fr;
                float v = acc[m][n][r];
                if constexpr (EPI & F_BIAS)   v += bias[col];
                if constexpr (EPI & F_RANK3)  v += rv0 * w1tail[col] + rv1 * w1tail[512 + col] + rv2 * w1tail[1024 + col];
                if constexpr (EPI & F_GELU)   v = gelu_f(v);
                if constexpr (EPI & F_RESIDH) v += b2f(srcH[(long)rr * 512 + col]);
                if constexpr (EPI & F_DEG)    v += dg * bias2[col];
                if constexpr (EPI & F_OUTF)   { if (real) Cf[(long)rr * 512 + col] = v; }
                if constexpr (EPI & F_OUTH)   Ch[(long)rr * ldh + col] = f2b(v);
            }
        }
    }
}

// ---------- CSR build ----------
__global__ __launch_bounds__(256) void deg_k(const int* __restrict__ ed, int* __restrict__ deg, int nE)
{
    const int e = blockIdx.x * 256 + threadIdx.x;
    if (e < nE) atomicAdd(&deg[ed[2 * e + 1]], 1);
}

// phase 1: per-block (256-wide) exclusive scan; block totals to partials
__global__ __launch_bounds__(256) void scan1_k(
    const int* __restrict__ deg, int* __restrict__ rowptr,
    int* __restrict__ partials, int n)
{
    __shared__ int tmp[256];
    const int tid = threadIdx.x;
    const int gid = blockIdx.x * 256 + tid;
    const int v = (gid < n) ? deg[gid] : 0;
    tmp[tid] = v;
    __syncthreads();
#pragma unroll
    for (int ofs = 1; ofs < 256; ofs <<= 1) {
        int t = (tid >= ofs) ? tmp[tid - ofs] : 0;
        __syncthreads();
        tmp[tid] += t;
        __syncthreads();
    }
    if (gid < n) rowptr[gid] = tmp[tid] - v;          // exclusive
    if (tid == 255) partials[blockIdx.x] = tmp[255];  // block total
}

// phase 2: single block scans the (<=256) block totals, exclusive
__global__ __launch_bounds__(256) void scan2_k(int* __restrict__ partials, int nb)
{
    __shared__ int tmp[256];
    const int tid = threadIdx.x;
    const int v = (tid < nb) ? partials[tid] : 0;
    tmp[tid] = v;
    __syncthreads();
#pragma unroll
    for (int ofs = 1; ofs < 256; ofs <<= 1) {
        int t = (tid >= ofs) ? tmp[tid - ofs] : 0;
        __syncthreads();
        tmp[tid] += t;
        __syncthreads();
    }
    if (tid < nb) partials[tid] = tmp[tid] - v;       // exclusive offsets
}

// phase 3: add block offset (in place; one thread per element)
__global__ __launch_bounds__(256) void scan3_k(
    int* __restrict__ rowptr, const int* __restrict__ partials, int n)
{
    const int gid = blockIdx.x * 256 + threadIdx.x;
    if (gid < n) rowptr[gid] += partials[blockIdx.x];
}

__global__ __launch_bounds__(256) void scat_k(
    const int* __restrict__ ed, const int* __restrict__ rowptr,
    int* __restrict__ cursor, int* __restrict__ csr, int nE)
{
    const int e = blockIdx.x * 256 + threadIdx.x;
    if (e >= nE) return;
    const int t = ed[2 * e + 1];
    const int p = atomicAdd(&cursor[t], 1);
    csr[rowptr[t] + p] = ed[2 * e];
}

// ---------- gather: Hg[t] = bf16( sum_{s in in(t)} gelu(A[s] + B[t] + bm1) ) ----------
__global__ __launch_bounds__(256) void gather_k(
    const int* __restrict__ rowptr, const int* __restrict__ degv,
    const int* __restrict__ csr, const u16* __restrict__ AB,
    const float* __restrict__ bm1, u16* __restrict__ Hg, int nNodes)
{
    const int t = (blockIdx.x << 2) + (threadIdx.x >> 6);
    if (t >= nNodes) return;
    const int lane = threadIdx.x & 63;
    const int c = lane << 3;
    float acc[8] = {0.f, 0.f, 0.f, 0.f, 0.f, 0.f, 0.f, 0.f};
    const int d = degv[t];
    if (d > 0) {
        s16x8 bv = *(const s16x8*)(AB + (long)t * 1024 + 512 + c);
        const float4* bmv = (const float4*)(bm1 + c);
        float4 q0 = bmv[0], q1 = bmv[1];
        float base[8] = { q0.x, q0.y, q0.z, q0.w, q1.x, q1.y, q1.z, q1.w };
#pragma unroll
        for (int j = 0; j < 8; j++) base[j] += b2f((u16)bv[j]);
        const int p0 = rowptr[t];
        for (int i = 0; i < d; i++) {
            const int s = csr[p0 + i];
            s16x8 av = *(const s16x8*)(AB + (long)s * 1024 + c);
#pragma unroll
            for (int j = 0; j < 8; j++) acc[j] += gelu_f(b2f((u16)av[j]) + base[j]);
        }
    }
    s16x8 o;
#pragma unroll
    for (int j = 0; j < 8; j++) o[j] = (short)f2b(acc[j]);
    *(s16x8*)(Hg + (long)t * 512 + c) = o;
}

// ---------- f32 -> bf16 (flat, region beyond nSrc zero-filled) ----------
__global__ __launch_bounds__(256) void cvt_pad_k(
    const float* __restrict__ src, u16* __restrict__ dst, long nSrc, long nTot)
{
    const long i = ((long)blockIdx.x * 256 + threadIdx.x) * 8;
    if (i >= nTot) return;
    s16x8 v;
    if (i + 8 <= nSrc) {
        const float4* s4 = (const float4*)(src + i);
        float4 a = s4[0], b = s4[1];
        v[0] = (short)f2b(a.x); v[1] = (short)f2b(a.y); v[2] = (short)f2b(a.z); v[3] = (short)f2b(a.w);
        v[4] = (short)f2b(b.x); v[5] = (short)f2b(b.y); v[6] = (short)f2b(b.z); v[7] = (short)f2b(b.w);
    } else {
#pragma unroll
        for (int j = 0; j < 8; j++) v[j] = (i + j < nSrc) ? (short)f2b(src[i + j]) : (short)0;
    }
    *(s16x8*)(dst + i) = v;
}

// ---------- weight transpose + convert: Wt[n*K+k] = bf16(W[(k+off)*N + n]) ----------
__global__ __launch_bounds__(256) void wtrans_k(
    const float* __restrict__ W, u16* __restrict__ Wt, int K, int N, int rowOff)
{
    const int idx = blockIdx.x * 256 + threadIdx.x;
    if (idx >= K * N) return;
    const int n = idx / K, k = idx % K;
    Wt[idx] = f2b(W[(long)(k + rowOff) * N + n]);
}

extern "C" void kernel_launch(void* const* d_in, const int* in_sizes, int n_in,
                              void* d_out, int out_size, void* d_ws, size_t ws_size,
                              hipStream_t stream)
{
    const float* nodef = (const float*)d_in[0];
    const float* river = (const float*)d_in[1];
    const int*   edges = (const int*)d_in[2];
    const float* W1  = (const float*)d_in[3];
    const float* b1  = (const float*)d_in[4];
    const float* W2  = (const float*)d_in[5];
    const float* b2  = (const float*)d_in[6];
    const float* Wm1 = (const float*)d_in[7];
    const float* bm1 = (const float*)d_in[8];
    const float* Wm2 = (const float*)d_in[9];
    const float* bm2 = (const float*)d_in[10];
    float* out = (float*)d_out;
    (void)n_in; (void)out_size;

    const int M = 50000, Mpad = 50048, H = 512;
    const int nE = in_sizes[2] / 2;
    const size_t nElem = (size_t)Mpad * H;
    const size_t nOut  = (size_t)M * H;

    char* ws = (char*)d_ws;
    size_t off = 0;
    auto alloc = [&](size_t bytes) { void* p = ws + off; off += (bytes + 255) & ~(size_t)255; return p; };
    u16* feats16 = (u16*)alloc(nElem * 2);            // running features (bf16 residual carrier)
    u16* AB16    = (u16*)alloc(nElem * 4);            // [Mpad][1024]: A | B (nf16 early)
    u16* Hg16    = (u16*)alloc(nElem * 2);            // gather output / h1
    u16* W1t     = (u16*)alloc(512 * 512 * 2);
    u16* W2t     = (u16*)alloc(512 * 512 * 2);
    u16* Wm1ct   = (u16*)alloc(1024 * 512 * 2);
    u16* Wm2t    = (u16*)alloc(512 * 512 * 2);
    int* deg     = (int*)alloc((size_t)Mpad * 4);
    int* rowptr  = (int*)alloc((size_t)Mpad * 4);
    int* cursor  = (int*)alloc((size_t)Mpad * 4);
    int* csr     = (int*)alloc((size_t)nE * 4);
    int* partials= (int*)alloc(256 * 4);
    const size_t NEED = off;                          // ~209 MB (confirmed fits)

    if (ws_size < NEED) return;                       // tripwire: clean absmax fail

    const int scanBlocks = (Mpad + 255) / 256;        // 196
    const dim3 ggrid(4, Mpad / 128, 1);
    const dim3 ggridAB(8, Mpad / 128, 1);
    const dim3 gblk(256, 1, 1);
    const int cvtBlocks = (int)(nElem / 8 / 256);

    // CSR build (edges fixed; rebuilt every call for determinism)
    hipMemsetAsync(deg, 0, (size_t)Mpad * 4, stream);
    hipMemsetAsync(cursor, 0, (size_t)Mpad * 4, stream);
    deg_k<<<dim3((nE + 255) / 256), gblk, 0, stream>>>(edges, deg, nE);
    scan1_k<<<dim3(scanBlocks), gblk, 0, stream>>>(deg, rowptr, partials, Mpad);
    scan2_k<<<dim3(1), gblk, 0, stream>>>(partials, scanBlocks);
    scan3_k<<<dim3(scanBlocks), gblk, 0, stream>>>(rowptr, partials, Mpad);
    scat_k<<<dim3((nE + 255) / 256), gblk, 0, stream>>>(edges, rowptr, cursor, csr, nE);

    // weights -> transposed bf16
    wtrans_k<<<dim3(1024), gblk, 0, stream>>>(W1,  W1t,             512, 512, 0);
    wtrans_k<<<dim3(1024), gblk, 0, stream>>>(W2,  W2t,             512, 512, 0);
    wtrans_k<<<dim3(1024), gblk, 0, stream>>>(Wm1, Wm1ct,           512, 512, 0);
    wtrans_k<<<dim3(1024), gblk, 0, stream>>>(Wm1, Wm1ct + 512*512, 512, 512, 512);
    wtrans_k<<<dim3(1024), gblk, 0, stream>>>(Wm2, Wm2t,            512, 512, 0);

    // node_features -> bf16 (flat [Mpad][512] in AB16 first half, padded rows zero)
    cvt_pad_k<<<dim3(cvtBlocks), gblk, 0, stream>>>(nodef, AB16, (long)nOut, (long)nElem);

    // h1 = gelu(x @ W1 + b1 + river @ W1tail) -> Hg16
    gemm_k<F_BIAS | F_RANK3 | F_GELU | F_OUTH><<<ggrid, gblk, 0, stream>>>(
        AB16, W1t, nullptr, Hg16, nullptr, b1, nullptr, nullptr, river, W1 + 512 * 512, M, 512);
    // feats16 = h1 @ W2 + b2  (bf16 only)
    gemm_k<F_BIAS | F_OUTH><<<ggrid, gblk, 0, stream>>>(
        Hg16, W2t, nullptr, feats16, nullptr, b2, nullptr, nullptr, nullptr, nullptr, M, 512);

    for (int r = 0; r < 3; r++) {
        // AB = feats @ [Wm1_top | Wm1_bot]  (N=1024 combined)
        gemm_k<F_OUTH><<<ggridAB, gblk, 0, stream>>>(
            feats16, Wm1ct, nullptr, AB16, nullptr, nullptr, nullptr, nullptr, nullptr, nullptr, M, 1024);
        // Hg[t] = sum_in gelu(A[s] + B[t] + bm1)
        gather_k<<<dim3(Mpad / 4), gblk, 0, stream>>>(rowptr, deg, csr, AB16, bm1, Hg16, Mpad);
        // feats = feats + Hg @ Wm2 + deg * bm2
        if (r < 2)
            gemm_k<F_RESIDH | F_DEG | F_OUTH><<<ggrid, gblk, 0, stream>>>(
                Hg16, Wm2t, nullptr, feats16, feats16, nullptr, bm2, deg, nullptr, nullptr, M, 512);
        else
            gemm_k<F_RESIDH | F_DEG | F_OUTF><<<ggrid, gblk, 0, stream>>>(
                Hg16, Wm2t, out, nullptr, feats16, nullptr, bm2, deg, nullptr, nullptr, M, 512);
    }
}

// Round 7
// 671.205 us; speedup vs baseline: 10.4822x; 1.1062x over previous
//
#include <hip/hip_runtime.h>
#include <hip/hip_bf16.h>
#include <cstdint>

using u16 = unsigned short;
typedef short s16x8 __attribute__((ext_vector_type(8)));
typedef float f32x4 __attribute__((ext_vector_type(4)));

// ---------- helpers ----------
__device__ __forceinline__ float b2f(u16 b) {
    union { unsigned u; float f; } z; z.u = ((unsigned)b) << 16; return z.f;
}
__device__ __forceinline__ u16 f2b(float f) {
    union { float f; unsigned u; } z; z.f = f;
    return (u16)((z.u + 0x7fffu + ((z.u >> 16) & 1u)) >> 16);
}
__device__ __forceinline__ float gelu_f(float x) {
    return 0.5f * x * (1.0f + erff(x * 0.70710678118654752440f));
}
__device__ __forceinline__ void gl2lds16(const void* g, void* l) {
    __builtin_amdgcn_global_load_lds(
        (const __attribute__((address_space(1))) void*)g,
        (__attribute__((address_space(3))) void*)l, 16, 0, 0);
}

enum { F_BIAS = 1, F_GELU = 2, F_RANK3 = 4, F_RESIDH = 8,
       F_DEG = 16, F_OUTF = 32, F_OUTH = 64 };

// ---------- GEMM: C = epilogue(A_bf16[M x 512] @ Bt_bf16[N x 512]^T) ----------
// Flat 1-D grid + bijective XCD swizzle (m204): workgroup w runs on XCD w%8,
// so giving XCD x the contiguous swz-range [x-chunk] makes all col-blocks of
// a row-tile land on ONE XCD's private L2 (R6 showed 4x A re-fetch because
// round-robin XCD assignment split them across 8 non-coherent L2s).
// swz layout: rowblk = swz >> gxShift, colblk = swz & (gx-1).
template<int EPI>
__global__ __launch_bounds__(256, 4) void gemm_k(
    const u16* __restrict__ A, const u16* __restrict__ Bt,
    float* __restrict__ Cf, u16* __restrict__ Ch,
    const u16* __restrict__ srcH,
    const float* __restrict__ bias, const float* __restrict__ bias2,
    const int* __restrict__ deg, const float* __restrict__ river,
    const float* __restrict__ w1tail, int Mreal, int ldh, int gxShift)
{
    __shared__ __align__(16) u16 As[128 * 32];
    __shared__ __align__(16) u16 Bs[128 * 32];

    // bijective XCD swizzle
    const int nwg  = gridDim.x;
    const int orig = blockIdx.x;
    const int xcd  = orig & 7;
    const int i    = orig >> 3;
    const int q    = nwg >> 3;
    const int r    = nwg & 7;
    const int swz  = (xcd < r) ? (xcd * (q + 1) + i) : (r * (q + 1) + (xcd - r) * q + i);
    const int rowblk = swz >> gxShift;
    const int colblk = swz & ((1 << gxShift) - 1);

    const int tid  = threadIdx.x;
    const int lane = tid & 63;
    const int wid  = tid >> 6;
    const int wr   = wid >> 1;
    const int wc   = wid & 1;
    const int fr   = lane & 15;
    const int fq   = lane >> 4;

    const long arow = (long)rowblk * 128 + (wid << 4) + (lane >> 2);
    const long brow = (long)colblk * 128 + (wid << 4) + (lane >> 2);
    const int  kofs = (lane & 3) << 3;
    u16* asw = As + (wid << 9);
    u16* bsw = Bs + (wid << 9);

    f32x4 acc[4][4];
#pragma unroll
    for (int m = 0; m < 4; m++)
#pragma unroll
        for (int n = 0; n < 4; n++) { f32x4 z = {0.f, 0.f, 0.f, 0.f}; acc[m][n] = z; }

    for (int kt = 0; kt < 512; kt += 32) {
        gl2lds16(A  + arow * 512 + kt + kofs,        asw);
        gl2lds16(A  + (arow + 64) * 512 + kt + kofs, asw + 2048);
        gl2lds16(Bt + brow * 512 + kt + kofs,        bsw);
        gl2lds16(Bt + (brow + 64) * 512 + kt + kofs, bsw + 2048);
        __syncthreads();

        s16x8 af[4], bf[4];
#pragma unroll
        for (int m = 0; m < 4; m++)
            af[m] = *(const s16x8*)(As + (((wr << 6) + (m << 4) + fr) << 5) + (fq << 3));
#pragma unroll
        for (int n = 0; n < 4; n++)
            bf[n] = *(const s16x8*)(Bs + (((wc << 6) + (n << 4) + fr) << 5) + (fq << 3));
#pragma unroll
        for (int m = 0; m < 4; m++)
#pragma unroll
            for (int n = 0; n < 4; n++)
                acc[m][n] = __builtin_amdgcn_mfma_f32_16x16x32_bf16(af[m], bf[n], acc[m][n], 0, 0, 0);
        __syncthreads();
    }

    const int colbase = (colblk << 7) + (wc << 6);
#pragma unroll
    for (int m = 0; m < 4; m++) {
        const int row0 = (rowblk << 7) + (wr << 6) + (m << 4) + (fq << 2);
#pragma unroll
        for (int rI = 0; rI < 4; rI++) {
            const int rr = row0 + rI;
            const bool real = rr < Mreal;
            float rv0 = 0.f, rv1 = 0.f, rv2 = 0.f;
            if constexpr (EPI & F_RANK3) {
                if (real) { rv0 = river[rr * 3]; rv1 = river[rr * 3 + 1]; rv2 = river[rr * 3 + 2]; }
            }
            float dg = 0.f;
            if constexpr (EPI & F_DEG) { if (real) dg = (float)deg[rr]; }
#pragma unroll
            for (int n = 0; n < 4; n++) {
                const int col = colbase + (n << 4) + fr;
                float v = acc[m][n][rI];
                if constexpr (EPI & F_BIAS)   v += bias[col];
                if constexpr (EPI & F_RANK3)  v += rv0 * w1tail[col] + rv1 * w1tail[512 + col] + rv2 * w1tail[1024 + col];
                if constexpr (EPI & F_GELU)   v = gelu_f(v);
                if constexpr (EPI & F_RESIDH) v += b2f(srcH[(long)rr * 512 + col]);
                if constexpr (EPI & F_DEG)    v += dg * bias2[col];
                if constexpr (EPI & F_OUTF)   { if (real) Cf[(long)rr * 512 + col] = v; }
                if constexpr (EPI & F_OUTH)   Ch[(long)rr * ldh + col] = f2b(v);
            }
        }
    }
}

// ---------- CSR build ----------
__global__ __launch_bounds__(256) void deg_k(const int* __restrict__ ed, int* __restrict__ deg, int nE)
{
    const int e = blockIdx.x * 256 + threadIdx.x;
    if (e < nE) atomicAdd(&deg[ed[2 * e + 1]], 1);
}

__global__ __launch_bounds__(256) void scan1_k(
    const int* __restrict__ deg, int* __restrict__ rowptr,
    int* __restrict__ partials, int n)
{
    __shared__ int tmp[256];
    const int tid = threadIdx.x;
    const int gid = blockIdx.x * 256 + tid;
    const int v = (gid < n) ? deg[gid] : 0;
    tmp[tid] = v;
    __syncthreads();
#pragma unroll
    for (int ofs = 1; ofs < 256; ofs <<= 1) {
        int t = (tid >= ofs) ? tmp[tid - ofs] : 0;
        __syncthreads();
        tmp[tid] += t;
        __syncthreads();
    }
    if (gid < n) rowptr[gid] = tmp[tid] - v;
    if (tid == 255) partials[blockIdx.x] = tmp[255];
}

__global__ __launch_bounds__(256) void scan2_k(int* __restrict__ partials, int nb)
{
    __shared__ int tmp[256];
    const int tid = threadIdx.x;
    const int v = (tid < nb) ? partials[tid] : 0;
    tmp[tid] = v;
    __syncthreads();
#pragma unroll
    for (int ofs = 1; ofs < 256; ofs <<= 1) {
        int t = (tid >= ofs) ? tmp[tid - ofs] : 0;
        __syncthreads();
        tmp[tid] += t;
        __syncthreads();
    }
    if (tid < nb) partials[tid] = tmp[tid] - v;
}

__global__ __launch_bounds__(256) void scan3_k(
    int* __restrict__ rowptr, const int* __restrict__ partials, int n)
{
    const int gid = blockIdx.x * 256 + threadIdx.x;
    if (gid < n) rowptr[gid] += partials[blockIdx.x];
}

__global__ __launch_bounds__(256) void scat_k(
    const int* __restrict__ ed, const int* __restrict__ rowptr,
    int* __restrict__ cursor, int* __restrict__ csr, int nE)
{
    const int e = blockIdx.x * 256 + threadIdx.x;
    if (e >= nE) return;
    const int t = ed[2 * e + 1];
    const int p = atomicAdd(&cursor[t], 1);
    csr[rowptr[t] + p] = ed[2 * e];
}

// ---------- gather: Hg[t] = bf16( sum_{s in in(t)} gelu(A[s] + B[t] + bm1) ) ----------
__global__ __launch_bounds__(256) void gather_k(
    const int* __restrict__ rowptr, const int* __restrict__ degv,
    const int* __restrict__ csr, const u16* __restrict__ AB,
    const float* __restrict__ bm1, u16* __restrict__ Hg, int nNodes)
{
    const int t = (blockIdx.x << 2) + (threadIdx.x >> 6);
    if (t >= nNodes) return;
    const int lane = threadIdx.x & 63;
    const int c = lane << 3;
    float acc[8] = {0.f, 0.f, 0.f, 0.f, 0.f, 0.f, 0.f, 0.f};
    const int d = degv[t];
    if (d > 0) {
        s16x8 bv = *(const s16x8*)(AB + (long)t * 1024 + 512 + c);
        const float4* bmv = (const float4*)(bm1 + c);
        float4 q0 = bmv[0], q1 = bmv[1];
        float base[8] = { q0.x, q0.y, q0.z, q0.w, q1.x, q1.y, q1.z, q1.w };
#pragma unroll
        for (int j = 0; j < 8; j++) base[j] += b2f((u16)bv[j]);
        const int p0 = rowptr[t];
        for (int i = 0; i < d; i++) {
            const int s = csr[p0 + i];
            s16x8 av = *(const s16x8*)(AB + (long)s * 1024 + c);
#pragma unroll
            for (int j = 0; j < 8; j++) acc[j] += gelu_f(b2f((u16)av[j]) + base[j]);
        }
    }
    s16x8 o;
#pragma unroll
    for (int j = 0; j < 8; j++) o[j] = (short)f2b(acc[j]);
    *(s16x8*)(Hg + (long)t * 512 + c) = o;
}

// ---------- f32 -> bf16 (flat, region beyond nSrc zero-filled) ----------
__global__ __launch_bounds__(256) void cvt_pad_k(
    const float* __restrict__ src, u16* __restrict__ dst, long nSrc, long nTot)
{
    const long i = ((long)blockIdx.x * 256 + threadIdx.x) * 8;
    if (i >= nTot) return;
    s16x8 v;
    if (i + 8 <= nSrc) {
        const float4* s4 = (const float4*)(src + i);
        float4 a = s4[0], b = s4[1];
        v[0] = (short)f2b(a.x); v[1] = (short)f2b(a.y); v[2] = (short)f2b(a.z); v[3] = (short)f2b(a.w);
        v[4] = (short)f2b(b.x); v[5] = (short)f2b(b.y); v[6] = (short)f2b(b.z); v[7] = (short)f2b(b.w);
    } else {
#pragma unroll
        for (int j = 0; j < 8; j++) v[j] = (i + j < nSrc) ? (short)f2b(src[i + j]) : (short)0;
    }
    *(s16x8*)(dst + i) = v;
}

// ---------- weight transpose + convert: Wt[n*K+k] = bf16(W[(k+off)*N + n]) ----------
__global__ __launch_bounds__(256) void wtrans_k(
    const float* __restrict__ W, u16* __restrict__ Wt, int K, int N, int rowOff)
{
    const int idx = blockIdx.x * 256 + threadIdx.x;
    if (idx >= K * N) return;
    const int n = idx / K, k = idx % K;
    Wt[idx] = f2b(W[(long)(k + rowOff) * N + n]);
}

extern "C" void kernel_launch(void* const* d_in, const int* in_sizes, int n_in,
                              void* d_out, int out_size, void* d_ws, size_t ws_size,
                              hipStream_t stream)
{
    const float* nodef = (const float*)d_in[0];
    const float* river = (const float*)d_in[1];
    const int*   edges = (const int*)d_in[2];
    const float* W1  = (const float*)d_in[3];
    const float* b1  = (const float*)d_in[4];
    const float* W2  = (const float*)d_in[5];
    const float* b2  = (const float*)d_in[6];
    const float* Wm1 = (const float*)d_in[7];
    const float* bm1 = (const float*)d_in[8];
    const float* Wm2 = (const float*)d_in[9];
    const float* bm2 = (const float*)d_in[10];
    float* out = (float*)d_out;
    (void)n_in; (void)out_size;

    const int M = 50000, Mpad = 50048, H = 512;
    const int nE = in_sizes[2] / 2;
    const size_t nElem = (size_t)Mpad * H;
    const size_t nOut  = (size_t)M * H;

    char* ws = (char*)d_ws;
    size_t off = 0;
    auto alloc = [&](size_t bytes) { void* p = ws + off; off += (bytes + 255) & ~(size_t)255; return p; };
    u16* feats16 = (u16*)alloc(nElem * 2);            // running features (bf16 residual carrier)
    u16* AB16    = (u16*)alloc(nElem * 4);            // [Mpad][1024]: A | B (nf16 early)
    u16* Hg16    = (u16*)alloc(nElem * 2);            // gather output / h1
    u16* W1t     = (u16*)alloc(512 * 512 * 2);
    u16* W2t     = (u16*)alloc(512 * 512 * 2);
    u16* Wm1ct   = (u16*)alloc(1024 * 512 * 2);
    u16* Wm2t    = (u16*)alloc(512 * 512 * 2);
    int* deg     = (int*)alloc((size_t)Mpad * 4);
    int* rowptr  = (int*)alloc((size_t)Mpad * 4);
    int* cursor  = (int*)alloc((size_t)Mpad * 4);
    int* csr     = (int*)alloc((size_t)nE * 4);
    int* partials= (int*)alloc(256 * 4);
    const size_t NEED = off;                          // ~209 MB (confirmed fits)

    if (ws_size < NEED) return;                       // tripwire: clean absmax fail

    const int scanBlocks = (Mpad + 255) / 256;        // 196
    const int MB = Mpad / 128;                        // 391 row-tiles
    const dim3 g512(MB * 4, 1, 1);                    // flat, gxShift=2
    const dim3 g1024(MB * 8, 1, 1);                   // flat, gxShift=3
    const dim3 gblk(256, 1, 1);
    const int cvtBlocks = (int)(nElem / 8 / 256);

    // CSR build (edges fixed; rebuilt every call for determinism)
    hipMemsetAsync(deg, 0, (size_t)Mpad * 4, stream);
    hipMemsetAsync(cursor, 0, (size_t)Mpad * 4, stream);
    deg_k<<<dim3((nE + 255) / 256), gblk, 0, stream>>>(edges, deg, nE);
    scan1_k<<<dim3(scanBlocks), gblk, 0, stream>>>(deg, rowptr, partials, Mpad);
    scan2_k<<<dim3(1), gblk, 0, stream>>>(partials, scanBlocks);
    scan3_k<<<dim3(scanBlocks), gblk, 0, stream>>>(rowptr, partials, Mpad);
    scat_k<<<dim3((nE + 255) / 256), gblk, 0, stream>>>(edges, rowptr, cursor, csr, nE);

    // weights -> transposed bf16
    wtrans_k<<<dim3(1024), gblk, 0, stream>>>(W1,  W1t,             512, 512, 0);
    wtrans_k<<<dim3(1024), gblk, 0, stream>>>(W2,  W2t,             512, 512, 0);
    wtrans_k<<<dim3(1024), gblk, 0, stream>>>(Wm1, Wm1ct,           512, 512, 0);
    wtrans_k<<<dim3(1024), gblk, 0, stream>>>(Wm1, Wm1ct + 512*512, 512, 512, 512);
    wtrans_k<<<dim3(1024), gblk, 0, stream>>>(Wm2, Wm2t,            512, 512, 0);

    // node_features -> bf16 (flat [Mpad][512] in AB16 first half, padded rows zero)
    cvt_pad_k<<<dim3(cvtBlocks), gblk, 0, stream>>>(nodef, AB16, (long)nOut, (long)nElem);

    // h1 = gelu(x @ W1 + b1 + river @ W1tail) -> Hg16
    gemm_k<F_BIAS | F_RANK3 | F_GELU | F_OUTH><<<g512, gblk, 0, stream>>>(
        AB16, W1t, nullptr, Hg16, nullptr, b1, nullptr, nullptr, river, W1 + 512 * 512, M, 512, 2);
    // feats16 = h1 @ W2 + b2  (bf16 only)
    gemm_k<F_BIAS | F_OUTH><<<g512, gblk, 0, stream>>>(
        Hg16, W2t, nullptr, feats16, nullptr, b2, nullptr, nullptr, nullptr, nullptr, M, 512, 2);

    for (int r = 0; r < 3; r++) {
        // AB = feats @ [Wm1_top | Wm1_bot]  (N=1024 combined)
        gemm_k<F_OUTH><<<g1024, gblk, 0, stream>>>(
            feats16, Wm1ct, nullptr, AB16, nullptr, nullptr, nullptr, nullptr, nullptr, nullptr, M, 1024, 3);
        // Hg[t] = sum_in gelu(A[s] + B[t] + bm1)
        gather_k<<<dim3(Mpad / 4), gblk, 0, stream>>>(rowptr, deg, csr, AB16, bm1, Hg16, Mpad);
        // feats = feats + Hg @ Wm2 + deg * bm2
        if (r < 2)
            gemm_k<F_RESIDH | F_DEG | F_OUTH><<<g512, gblk, 0, stream>>>(
                Hg16, Wm2t, nullptr, feats16, feats16, nullptr, bm2, deg, nullptr, nullptr, M, 512, 2);
        else
            gemm_k<F_RESIDH | F_DEG | F_OUTF><<<g512, gblk, 0, stream>>>(
                Hg16, Wm2t, out, nullptr, feats16, nullptr, bm2, deg, nullptr, nullptr, M, 512, 2);
    }
}